// Round 4
// baseline (2973.772 us; speedup 1.0000x reference)
//
#include <hip/hip_runtime.h>
#include <hip/hip_bf16.h>
#include <math.h>

// Problem constants (fixed by setup_inputs)
#define SEQ    2048
#define BATCH  4
#define XDIM   16
#define DMODEL 256
#define NHEAD  8
#define DH     32
#define DFF    512
#define NLAYER 2
#define MPOS   1024
#define ROWS   (SEQ*BATCH)   // 8192
#define NBLK   768           // 3 blocks/CU * 256 CUs, co-resident by construction

#define ATT_SCALE 0.17677669529663687f  // 1/sqrt(32)
#define BK 32

typedef __attribute__((ext_vector_type(8))) short bf16x8;  // MFMA A/B frag
typedef __attribute__((ext_vector_type(4))) float f32x4;   // MFMA C/D frag

__device__ __forceinline__ float gelu_exact(float x) {
    return 0.5f * x * (1.0f + erff(x * 0.70710678118654752f));
}
__device__ __forceinline__ short f2bf(float f) {
    unsigned int u = __float_as_uint(f);
    u += 0x7FFFu + ((u >> 16) & 1u);
    return (short)(u >> 16);
}
__device__ __forceinline__ float bf2f(unsigned short u) {
    return __uint_as_float(((unsigned int)u) << 16);
}
__device__ __forceinline__ void gload16(const unsigned short* g, unsigned short* l) {
    __builtin_amdgcn_global_load_lds(
        (const __attribute__((address_space(1))) unsigned int*)g,
        (__attribute__((address_space(3))) unsigned int*)l, 16, 0, 0);
}
#define VMWAIT(N) asm volatile("s_waitcnt vmcnt(" #N ")" ::: "memory")
__device__ __forceinline__ void pipe_barrier() {
    __builtin_amdgcn_sched_barrier(0);
    __builtin_amdgcn_s_barrier();
    __builtin_amdgcn_sched_barrier(0);
}

// device-scope generation barrier (the cooperative-groups protocol):
// release fence -> arrive -> last resets count, bumps gen -> spin on gen -> acquire fence.
__device__ __forceinline__ void gbar(int* cnt, int* gen) {
    __syncthreads();
    __threadfence();   // release: drain this block's stores to device scope
    if (threadIdx.x == 0) {
        int g = __hip_atomic_load(gen, __ATOMIC_RELAXED, __HIP_MEMORY_SCOPE_AGENT);
        int v = __hip_atomic_fetch_add(cnt, 1, __ATOMIC_ACQ_REL, __HIP_MEMORY_SCOPE_AGENT);
        if (v == NBLK - 1) {
            __hip_atomic_store(cnt, 0, __ATOMIC_RELAXED, __HIP_MEMORY_SCOPE_AGENT);
            __hip_atomic_store(gen, g + 1, __ATOMIC_RELEASE, __HIP_MEMORY_SCOPE_AGENT);
        } else {
            while (__hip_atomic_load(gen, __ATOMIC_ACQUIRE, __HIP_MEMORY_SCOPE_AGENT) == g)
                __builtin_amdgcn_s_sleep(2);
        }
    }
    __syncthreads();
    __threadfence();   // acquire: invalidate caches before reading producers' data
}

// ---- shared-memory union, max 36864 B (3 blocks/CU: 3x36.9 = 110.6 KB <= 160 KB)
struct SmemG {  // qkv / ff1: 3-buffer 128x64 tiles             -> 36864 B
    unsigned short As[3][128][BK];
    unsigned short Bs[3][64][BK];
};
struct SmemL {  // gemm_ln / head: 2-buffer 16-row tiles        -> 35328 B
    unsigned short As[2][16][BK];
    unsigned short Bs[2][256][BK];
    float sP[4][16];
    float qP[4][16];
};
struct SmemA {  // attention                                    -> 28672 B
    unsigned short Kt[2][64][40];
    unsigned short Vt[2][32][72];
    unsigned short Pt[4][16][72];
};
struct SmemE {  // encoder                                      -> 544 B
    float xs[8][16];
    float ys[8];
};

__global__ __launch_bounds__(256, 3) void mega(
    const float* __restrict__ x, const float* __restrict__ y,
    const float* __restrict__ xw, const float* __restrict__ xb,
    const float* __restrict__ yw, const float* __restrict__ yb,
    const float* __restrict__ in_proj_w, const float* __restrict__ in_proj_b,
    const float* __restrict__ out_proj_w, const float* __restrict__ out_proj_b,
    const float* __restrict__ ln1_g, const float* __restrict__ ln1_b,
    const float* __restrict__ lin1_w, const float* __restrict__ lin1_b,
    const float* __restrict__ lin2_w, const float* __restrict__ lin2_b,
    const float* __restrict__ ln2_g, const float* __restrict__ ln2_b,
    const float* __restrict__ head_w1, const float* __restrict__ head_b1,
    const float* __restrict__ head_w2, const float* __restrict__ head_b2,
    float* __restrict__ h, unsigned short* __restrict__ hb,
    unsigned short* __restrict__ ffb, unsigned short* __restrict__ attb,
    unsigned short* __restrict__ Qg, unsigned short* __restrict__ Kg,
    unsigned short* __restrict__ Vg,
    unsigned short* __restrict__ Wqkv, unsigned short* __restrict__ Wout,
    unsigned short* __restrict__ Wl1, unsigned short* __restrict__ Wl2,
    unsigned short* __restrict__ Wh1,
    float* __restrict__ out, int* __restrict__ bar)
{
    __shared__ __align__(16) unsigned char smem[36864];
    int* cnt = bar;
    int* gen = bar + 16;

    const int bid  = blockIdx.x;
    const int tid  = threadIdx.x;
    const int w    = tid >> 6;
    const int lane = tid & 63;
    const int col  = lane & 15;
    const int quad = lane >> 4;
    const int l4   = lane >> 2;
    const int c8   = (lane & 3) * 8;

    // ================= stage: encoder + weight casts =================
    {
        SmemE* sm = (SmemE*)smem;
        const int d = tid;
        float wreg[XDIM];
        #pragma unroll
        for (int k = 0; k < XDIM; ++k) wreg[k] = xw[d*XDIM + k];
        const float xbv = xb[d], ywv = yw[d], ybv = yb[d];
        for (int grp = bid; grp < ROWS/8; grp += NBLK) {
            if (tid < 128) sm->xs[tid>>4][tid&15] = x[(size_t)(grp*8 + (tid>>4))*XDIM + (tid&15)];
            if (tid < 8)   sm->ys[tid] = y[grp*8 + tid];
            __syncthreads();
            #pragma unroll
            for (int r = 0; r < 8; ++r) {
                int row = grp*8 + r;
                float acc = xbv;
                #pragma unroll
                for (int k = 0; k < XDIM; ++k) acc = fmaf(sm->xs[r][k], wreg[k], acc);
                if ((row >> 2) < MPOS) acc += sm->ys[r]*ywv + ybv;
                h[(size_t)row*DMODEL + d]  = acc;
                hb[(size_t)row*DMODEL + d] = (unsigned short)f2bf(acc);
            }
            __syncthreads();
        }
        // weight casts f32 -> bf16 (8 elements per index)
        int i = bid*256 + tid;
        if (i < 147456) {
            const float* s; unsigned short* dd; int off;
            if      (i <  49152) { s = in_proj_w;  dd = Wqkv; off = i; }
            else if (i <  65536) { s = out_proj_w; dd = Wout; off = i - 49152; }
            else if (i <  98304) { s = lin1_w;     dd = Wl1;  off = i - 65536; }
            else if (i < 131072) { s = lin2_w;     dd = Wl2;  off = i - 98304; }
            else                 { s = head_w1;    dd = Wh1;  off = i - 131072; }
            float4 a = *(const float4*)(s + (size_t)off*8);
            float4 c = *(const float4*)(s + (size_t)off*8 + 4);
            ushort4 u0, u1;
            u0.x=(unsigned short)f2bf(a.x); u0.y=(unsigned short)f2bf(a.y);
            u0.z=(unsigned short)f2bf(a.z); u0.w=(unsigned short)f2bf(a.w);
            u1.x=(unsigned short)f2bf(c.x); u1.y=(unsigned short)f2bf(c.y);
            u1.z=(unsigned short)f2bf(c.z); u1.w=(unsigned short)f2bf(c.w);
            *(ushort4*)(dd + (size_t)off*8)     = u0;
            *(ushort4*)(dd + (size_t)off*8 + 4) = u1;
        }
    }
    gbar(cnt, gen);

    for (int l = 0; l < NLAYER; ++l) {
        // ================= stage: qkv GEMM (768 tiles, exact fit) =================
        {
            SmemG* sm = (SmemG*)smem;
            const unsigned short* Wl = Wqkv + (size_t)l*3*DMODEL*DMODEL;
            const float* bias = in_proj_b + l*3*DMODEL;
            int bx = bid % 12, by = bid / 12;
            int m0 = by * 128, n0 = bx * 64;

            f32x4 acc[2][4];
            #pragma unroll
            for (int i = 0; i < 2; ++i)
                #pragma unroll
                for (int j = 0; j < 4; ++j) acc[i][j] = (f32x4){0.f,0.f,0.f,0.f};

            const unsigned short* ga = hb + (size_t)(m0 + w*32 + l4)*DMODEL + c8;
            const unsigned short* gb = Wl + (size_t)(n0 + w*16 + l4)*DMODEL + c8;
            const int NS = DMODEL / BK;  // 8

            gload16(ga,                       &sm->As[0][w*32     ][0]);
            gload16(ga + (size_t)16*DMODEL,   &sm->As[0][w*32 + 16][0]);
            gload16(gb,                       &sm->Bs[0][w*16     ][0]);
            gload16(ga + BK,                      &sm->As[1][w*32     ][0]);
            gload16(ga + BK + (size_t)16*DMODEL,  &sm->As[1][w*32 + 16][0]);
            gload16(gb + BK,                      &sm->Bs[1][w*16     ][0]);

            int bcur = 0;
            for (int s = 0; s < NS; ++s) {
                if (s == NS - 1) { VMWAIT(0); } else { VMWAIT(3); }
                pipe_barrier();
                if (s + 2 < NS) {
                    int bpre = bcur + 2; if (bpre >= 3) bpre -= 3;
                    int k2 = (s + 2) * BK;
                    gload16(ga + k2,                      &sm->As[bpre][w*32     ][0]);
                    gload16(ga + k2 + (size_t)16*DMODEL,  &sm->As[bpre][w*32 + 16][0]);
                    gload16(gb + k2,                      &sm->Bs[bpre][w*16     ][0]);
                }
                bf16x8 af[2], bfr[4];
                #pragma unroll
                for (int i = 0; i < 2; ++i) af[i]  = *(const bf16x8*)&sm->As[bcur][w*32 + i*16 + col][quad*8];
                #pragma unroll
                for (int j = 0; j < 4; ++j) bfr[j] = *(const bf16x8*)&sm->Bs[bcur][j*16 + col][quad*8];
                #pragma unroll
                for (int i = 0; i < 2; ++i)
                    #pragma unroll
                    for (int j = 0; j < 4; ++j)
                        acc[i][j] = __builtin_amdgcn_mfma_f32_16x16x32_bf16(bfr[j], af[i], acc[i][j], 0, 0, 0);
                bcur = (bcur == 2) ? 0 : bcur + 1;
            }

            int region = n0 >> 8;   // 0=Q, 1=K, 2=V
            if (region < 2) {
                #pragma unroll
                for (int i = 0; i < 2; ++i) {
                    int m = m0 + w*32 + i*16 + col;
                    int s = m >> 2, bidx = m & 3;
                    #pragma unroll
                    for (int j = 0; j < 4; ++j) {
                        int ng = n0 + j*16 + quad*4;
                        float4 bi = *(const float4*)&bias[ng];
                        ushort4 u;
                        u.x=(unsigned short)f2bf(acc[i][j][0] + bi.x);
                        u.y=(unsigned short)f2bf(acc[i][j][1] + bi.y);
                        u.z=(unsigned short)f2bf(acc[i][j][2] + bi.z);
                        u.w=(unsigned short)f2bf(acc[i][j][3] + bi.w);
                        int np = ng - (region << 8);
                        int hh = np >> 5, d = np & 31;
                        int bh = bidx*NHEAD + hh;
                        if (region == 0)
                            *(ushort4*)(Qg + ((size_t)(bh*SEQ + s))*DH + d) = u;
                        else
                            *(ushort4*)(Kg + ((size_t)(bh*SEQ + s))*DH + d) = u;
                    }
                }
            } else {
                __syncthreads();   // all waves done with As before aliasing
                unsigned short* T3 = (unsigned short*)sm;   // 16 KB scratch
                #pragma unroll
                for (int i = 0; i < 2; ++i) {
                    int mi = w*32 + i*16 + col;
                    int ss = mi >> 2, bidx = mi & 3;
                    #pragma unroll
                    for (int j = 0; j < 4; ++j) {
                        int ni = j*16 + quad*4;
                        float4 bi = *(const float4*)&bias[n0 + ni];
                        T3[((ni    )*4 + bidx)*32 + ss] = (unsigned short)f2bf(acc[i][j][0] + bi.x);
                        T3[((ni + 1)*4 + bidx)*32 + ss] = (unsigned short)f2bf(acc[i][j][1] + bi.y);
                        T3[((ni + 2)*4 + bidx)*32 + ss] = (unsigned short)f2bf(acc[i][j][2] + bi.z);
                        T3[((ni + 3)*4 + bidx)*32 + ss] = (unsigned short)f2bf(acc[i][j][3] + bi.w);
                    }
                }
                __syncthreads();
                int sBase = m0 >> 2;
                #pragma unroll
                for (int r = 0; r < 4; ++r) {
                    int chunk = tid + 256*r;
                    int ln2_ = chunk >> 2, p = chunk & 3;
                    int d = ln2_ & 31, hh_l = (ln2_ >> 5) & 1, bidx = ln2_ >> 6;
                    int ni = hh_l*32 + d;
                    int hh = ((n0 & 255) + ni) >> 5;
                    int bh = bidx*NHEAD + hh;
                    uint4 val = *(const uint4*)&T3[(ni*4 + bidx)*32 + p*8];
                    *(uint4*)(Vg + ((size_t)(bh*DH + d))*SEQ + sBase + p*8) = val;
                }
            }
        }
        gbar(cnt, gen);

        // ================= stage: flash attention (1024 units, stride) ============
        {
            SmemA* sm = (SmemA*)smem;
            for (int u = bid; u < 1024; u += NBLK) {
                const int sl = u >> 3;
                const int bh = (u & 7) * 4 + (sl >> 5);
                const int qt = sl & 31;
                const int hh = bh & 7;
                const int b  = bh >> 3;
                const int q0 = qt * 64;

                const int q = q0 + 16*w + col;
                bf16x8 qf = *(const bf16x8*)(Qg + ((size_t)(bh*SEQ + q))*DH + quad*8);

                f32x4 O0 = {0.f,0.f,0.f,0.f};
                f32x4 O1 = {0.f,0.f,0.f,0.f};
                float lsum = 0.f;

                const int kRow = tid >> 2, kCh = (tid & 3) * 8;
                const int vD   = tid >> 3, vCh = (tid & 7) * 8;

                const int nT = 16 + ((q0 >= MPOS) ? 1 : 0);
                uint4 kreg = *(const uint4*)(Kg + ((size_t)(bh*SEQ + kRow))*DH + kCh);
                uint4 vreg = *(const uint4*)(Vg + ((size_t)(bh*DH + vD))*SEQ + vCh);

                for (int kt = 0; kt < nT; ++kt) {
                    const bool self = (kt == 16);
                    const int  p    = kt & 1;
                    *(uint4*)&sm->Kt[p][kRow][kCh] = kreg;
                    *(uint4*)&sm->Vt[p][vD][vCh]   = vreg;
                    __syncthreads();
                    if (kt + 1 < nT) {
                        int kn = (kt + 1 == 16) ? q0 : (kt + 1)*64;
                        kreg = *(const uint4*)(Kg + ((size_t)(bh*SEQ + kn + kRow))*DH + kCh);
                        vreg = *(const uint4*)(Vg + ((size_t)(bh*DH + vD))*SEQ + kn + vCh);
                    }
                    #pragma unroll
                    for (int mt = 0; mt < 4; ++mt) {
                        bf16x8 kf = *(const bf16x8*)&sm->Kt[p][mt*16 + col][quad*8];
                        f32x4 st = {0.f,0.f,0.f,0.f};
                        st = __builtin_amdgcn_mfma_f32_16x16x32_bf16(kf, qf, st, 0, 0, 0);
                        ushort4 pw;
                        #pragma unroll
                        for (int i = 0; i < 4; ++i) {
                            float pv = __expf(st[i]*ATT_SCALE);
                            if (self && (mt*16 + quad*4 + i != 16*w + col)) pv = 0.f;
                            unsigned short us = (unsigned short)f2bf(pv);
                            ((unsigned short*)&pw)[i] = us;
                            lsum += bf2f(us);
                        }
                        *(ushort4*)&sm->Pt[w][col][mt*16 + quad*4] = pw;
                    }
                    #pragma unroll
                    for (int c = 0; c < 2; ++c) {
                        bf16x8 pf = *(const bf16x8*)&sm->Pt[w][col][c*32 + quad*8];
                        bf16x8 v0 = *(const bf16x8*)&sm->Vt[p][col     ][c*32 + quad*8];
                        bf16x8 v1 = *(const bf16x8*)&sm->Vt[p][col + 16][c*32 + quad*8];
                        O0 = __builtin_amdgcn_mfma_f32_16x16x32_bf16(v0, pf, O0, 0, 0, 0);
                        O1 = __builtin_amdgcn_mfma_f32_16x16x32_bf16(v1, pf, O1, 0, 0, 0);
                    }
                }

                lsum += __shfl_xor(lsum, 16, 64);
                lsum += __shfl_xor(lsum, 32, 64);
                float inv = 1.0f / lsum;
                ushort4 u0, u1;
                #pragma unroll
                for (int i = 0; i < 4; ++i) {
                    ((unsigned short*)&u0)[i] = (unsigned short)f2bf(O0[i]*inv);
                    ((unsigned short*)&u1)[i] = (unsigned short)f2bf(O1[i]*inv);
                }
                unsigned short* op = attb + ((size_t)(q*BATCH + b))*DMODEL + hh*DH;
                *(ushort4*)(op + quad*4)      = u0;
                *(ushort4*)(op + 16 + quad*4) = u1;
                __syncthreads();   // smem reuse across units
            }
        }
        gbar(cnt, gen);

        // ================= stage: out-proj GEMM + residual + LN ===================
        {
            if (bid < ROWS/16) {
                SmemL* sm = (SmemL*)smem;
                const unsigned short* Wl = Wout + (size_t)l*DMODEL*DMODEL;
                const float* bias = out_proj_b + l*DMODEL;
                const float* gg   = ln1_g + l*DMODEL;
                const float* bb   = ln1_b + l*DMODEL;
                const int K = DMODEL, NS = K / BK;  // 8
                int m0 = bid * 16;

                f32x4 acc[4];
                #pragma unroll
                for (int j = 0; j < 4; ++j) acc[j] = (f32x4){0.f,0.f,0.f,0.f};

                const unsigned short* ga = attb + (size_t)(m0 + l4)*K + c8;
                const unsigned short* gb = Wl + (size_t)(w*64 + l4)*K + c8;

                #pragma unroll
                for (int pb = 0; pb < 2; ++pb) {
                    int k = pb * BK;
                    if (w == 0) gload16(ga + k, &sm->As[pb][0][0]);
                    #pragma unroll
                    for (int rr = 0; rr < 4; ++rr)
                        gload16(gb + k + (size_t)(rr*16)*K, &sm->Bs[pb][w*64 + rr*16][0]);
                }
                for (int s = 0; s < NS; ++s) {
                    int cur = s & 1;
                    if (s == NS - 1)  { VMWAIT(0); }
                    else if (w == 0)  { VMWAIT(5); }
                    else              { VMWAIT(4); }
                    pipe_barrier();
                    bf16x8 af = *(const bf16x8*)&sm->As[cur][col][quad*8];
                    #pragma unroll
                    for (int j = 0; j < 4; ++j) {
                        bf16x8 bfr = *(const bf16x8*)&sm->Bs[cur][w*64 + j*16 + col][quad*8];
                        acc[j] = __builtin_amdgcn_mfma_f32_16x16x32_bf16(bfr, af, acc[j], 0, 0, 0);
                    }
                    pipe_barrier();
                    if (s + 2 < NS) {
                        int k2 = (s + 2) * BK;
                        if (w == 0) gload16(ga + k2, &sm->As[cur][0][0]);
                        #pragma unroll
                        for (int rr = 0; rr < 4; ++rr)
                            gload16(gb + k2 + (size_t)(rr*16)*K, &sm->Bs[cur][w*64 + rr*16][0]);
                    }
                }

                int m = m0 + col;
                float v[4][4];
                float s = 0.f, q = 0.f;
                #pragma unroll
                for (int j = 0; j < 4; ++j) {
                    int n = w*64 + j*16 + quad*4;
                    float4 bi = *(const float4*)&bias[n];
                    float4 hv = *(const float4*)&h[(size_t)m*DMODEL + n];
                    float val0 = acc[j][0] + bi.x + hv.x;
                    float val1 = acc[j][1] + bi.y + hv.y;
                    float val2 = acc[j][2] + bi.z + hv.z;
                    float val3 = acc[j][3] + bi.w + hv.w;
                    v[j][0]=val0; v[j][1]=val1; v[j][2]=val2; v[j][3]=val3;
                    s += (val0+val1) + (val2+val3);
                    q += (val0*val0 + val1*val1) + (val2*val2 + val3*val3);
                }
                s += __shfl_xor(s, 16, 64); s += __shfl_xor(s, 32, 64);
                q += __shfl_xor(q, 16, 64); q += __shfl_xor(q, 32, 64);
                if (quad == 0) { sm->sP[w][col] = s; sm->qP[w][col] = q; }
                __syncthreads();
                float st = sm->sP[0][col] + sm->sP[1][col] + sm->sP[2][col] + sm->sP[3][col];
                float qt = sm->qP[0][col] + sm->qP[1][col] + sm->qP[2][col] + sm->qP[3][col];
                float mu   = st * (1.0f/DMODEL);
                float var  = qt * (1.0f/DMODEL) - mu*mu;
                float rstd = rsqrtf(var + 1e-5f);
                #pragma unroll
                for (int j = 0; j < 4; ++j) {
                    int n = w*64 + j*16 + quad*4;
                    float4 gv = *(const float4*)&gg[n];
                    float4 bv = *(const float4*)&bb[n];
                    float4 o;
                    o.x = (v[j][0]-mu)*rstd*gv.x + bv.x;
                    o.y = (v[j][1]-mu)*rstd*gv.y + bv.y;
                    o.z = (v[j][2]-mu)*rstd*gv.z + bv.z;
                    o.w = (v[j][3]-mu)*rstd*gv.w + bv.w;
                    *(float4*)&h[(size_t)m*DMODEL + n] = o;
                    ushort4 u;
                    u.x=(unsigned short)f2bf(o.x); u.y=(unsigned short)f2bf(o.y);
                    u.z=(unsigned short)f2bf(o.z); u.w=(unsigned short)f2bf(o.w);
                    *(ushort4*)(hb + (size_t)m*DMODEL + n) = u;
                }
            }
        }
        gbar(cnt, gen);

        // ================= stage: ff1 GEMM + gelu (512 tiles) =====================
        {
            if (bid < 512) {
                SmemG* sm = (SmemG*)smem;
                const unsigned short* Wl = Wl1 + (size_t)l*DFF*DMODEL;
                const float* bias = lin1_b + l*DFF;
                int bx = bid & 7, by = bid >> 3;
                int m0 = by * 128, n0 = bx * 64;
                const int K = DMODEL, NS = K / BK;  // 8

                f32x4 acc[2][4];
                #pragma unroll
                for (int i = 0; i < 2; ++i)
                    #pragma unroll
                    for (int j = 0; j < 4; ++j) acc[i][j] = (f32x4){0.f,0.f,0.f,0.f};

                const unsigned short* ga = hb + (size_t)(m0 + w*32 + l4)*K + c8;
                const unsigned short* gb = Wl + (size_t)(n0 + w*16 + l4)*K + c8;

                gload16(ga,                  &sm->As[0][w*32     ][0]);
                gload16(ga + (size_t)16*K,   &sm->As[0][w*32 + 16][0]);
                gload16(gb,                  &sm->Bs[0][w*16     ][0]);
                gload16(ga + BK,                 &sm->As[1][w*32     ][0]);
                gload16(ga + BK + (size_t)16*K,  &sm->As[1][w*32 + 16][0]);
                gload16(gb + BK,                 &sm->Bs[1][w*16     ][0]);

                int bcur = 0;
                for (int s = 0; s < NS; ++s) {
                    if (s == NS - 1) { VMWAIT(0); } else { VMWAIT(3); }
                    pipe_barrier();
                    if (s + 2 < NS) {
                        int bpre = bcur + 2; if (bpre >= 3) bpre -= 3;
                        int k2 = (s + 2) * BK;
                        gload16(ga + k2,                &sm->As[bpre][w*32     ][0]);
                        gload16(ga + k2 + (size_t)16*K, &sm->As[bpre][w*32 + 16][0]);
                        gload16(gb + k2,                &sm->Bs[bpre][w*16     ][0]);
                    }
                    bf16x8 af[2], bfr[4];
                    #pragma unroll
                    for (int i = 0; i < 2; ++i) af[i]  = *(const bf16x8*)&sm->As[bcur][w*32 + i*16 + col][quad*8];
                    #pragma unroll
                    for (int j = 0; j < 4; ++j) bfr[j] = *(const bf16x8*)&sm->Bs[bcur][j*16 + col][quad*8];
                    #pragma unroll
                    for (int i = 0; i < 2; ++i)
                        #pragma unroll
                        for (int j = 0; j < 4; ++j)
                            acc[i][j] = __builtin_amdgcn_mfma_f32_16x16x32_bf16(bfr[j], af[i], acc[i][j], 0, 0, 0);
                    bcur = (bcur == 2) ? 0 : bcur + 1;
                }

                #pragma unroll
                for (int i = 0; i < 2; ++i) {
                    int m = m0 + w*32 + i*16 + col;
                    #pragma unroll
                    for (int j = 0; j < 4; ++j) {
                        int n = n0 + j*16 + quad*4;
                        float4 bi = *(const float4*)&bias[n];
                        float v0 = gelu_exact(acc[i][j][0] + bi.x);
                        float v1 = gelu_exact(acc[i][j][1] + bi.y);
                        float v2 = gelu_exact(acc[i][j][2] + bi.z);
                        float v3 = gelu_exact(acc[i][j][3] + bi.w);
                        ushort4 u;
                        u.x=(unsigned short)f2bf(v0); u.y=(unsigned short)f2bf(v1);
                        u.z=(unsigned short)f2bf(v2); u.w=(unsigned short)f2bf(v3);
                        *(ushort4*)(ffb + (size_t)m*DFF + n) = u;
                    }
                }
            }
        }
        gbar(cnt, gen);

        // ================= stage: ff2 GEMM + residual + LN ========================
        {
            if (bid < ROWS/16) {
                SmemL* sm = (SmemL*)smem;
                const unsigned short* Wl = Wl2 + (size_t)l*DMODEL*DFF;
                const float* bias = lin2_b + l*DMODEL;
                const float* gg   = ln2_g + l*DMODEL;
                const float* bb   = ln2_b + l*DMODEL;
                const int K = DFF, NS = K / BK;  // 16
                int m0 = bid * 16;

                f32x4 acc[4];
                #pragma unroll
                for (int j = 0; j < 4; ++j) acc[j] = (f32x4){0.f,0.f,0.f,0.f};

                const unsigned short* ga = ffb + (size_t)(m0 + l4)*K + c8;
                const unsigned short* gb = Wl + (size_t)(w*64 + l4)*K + c8;

                #pragma unroll
                for (int pb = 0; pb < 2; ++pb) {
                    int k = pb * BK;
                    if (w == 0) gload16(ga + k, &sm->As[pb][0][0]);
                    #pragma unroll
                    for (int rr = 0; rr < 4; ++rr)
                        gload16(gb + k + (size_t)(rr*16)*K, &sm->Bs[pb][w*64 + rr*16][0]);
                }
                for (int s = 0; s < NS; ++s) {
                    int cur = s & 1;
                    if (s == NS - 1)  { VMWAIT(0); }
                    else if (w == 0)  { VMWAIT(5); }
                    else              { VMWAIT(4); }
                    pipe_barrier();
                    bf16x8 af = *(const bf16x8*)&sm->As[cur][col][quad*8];
                    #pragma unroll
                    for (int j = 0; j < 4; ++j) {
                        bf16x8 bfr = *(const bf16x8*)&sm->Bs[cur][w*64 + j*16 + col][quad*8];
                        acc[j] = __builtin_amdgcn_mfma_f32_16x16x32_bf16(bfr, af, acc[j], 0, 0, 0);
                    }
                    pipe_barrier();
                    if (s + 2 < NS) {
                        int k2 = (s + 2) * BK;
                        if (w == 0) gload16(ga + k2, &sm->As[cur][0][0]);
                        #pragma unroll
                        for (int rr = 0; rr < 4; ++rr)
                            gload16(gb + k2 + (size_t)(rr*16)*K, &sm->Bs[cur][w*64 + rr*16][0]);
                    }
                }

                int m = m0 + col;
                float v[4][4];
                float s = 0.f, q = 0.f;
                #pragma unroll
                for (int j = 0; j < 4; ++j) {
                    int n = w*64 + j*16 + quad*4;
                    float4 bi = *(const float4*)&bias[n];
                    float4 hv = *(const float4*)&h[(size_t)m*DMODEL + n];
                    float val0 = acc[j][0] + bi.x + hv.x;
                    float val1 = acc[j][1] + bi.y + hv.y;
                    float val2 = acc[j][2] + bi.z + hv.z;
                    float val3 = acc[j][3] + bi.w + hv.w;
                    v[j][0]=val0; v[j][1]=val1; v[j][2]=val2; v[j][3]=val3;
                    s += (val0+val1) + (val2+val3);
                    q += (val0*val0 + val1*val1) + (val2*val2 + val3*val3);
                }
                s += __shfl_xor(s, 16, 64); s += __shfl_xor(s, 32, 64);
                q += __shfl_xor(q, 16, 64); q += __shfl_xor(q, 32, 64);
                if (quad == 0) { sm->sP[w][col] = s; sm->qP[w][col] = q; }
                __syncthreads();
                float st = sm->sP[0][col] + sm->sP[1][col] + sm->sP[2][col] + sm->sP[3][col];
                float qt = sm->qP[0][col] + sm->qP[1][col] + sm->qP[2][col] + sm->qP[3][col];
                float mu   = st * (1.0f/DMODEL);
                float var  = qt * (1.0f/DMODEL) - mu*mu;
                float rstd = rsqrtf(var + 1e-5f);
                #pragma unroll
                for (int j = 0; j < 4; ++j) {
                    int n = w*64 + j*16 + quad*4;
                    float4 gv = *(const float4*)&gg[n];
                    float4 bv = *(const float4*)&bb[n];
                    float4 o;
                    o.x = (v[j][0]-mu)*rstd*gv.x + bv.x;
                    o.y = (v[j][1]-mu)*rstd*gv.y + bv.y;
                    o.z = (v[j][2]-mu)*rstd*gv.z + bv.z;
                    o.w = (v[j][3]-mu)*rstd*gv.w + bv.w;
                    *(float4*)&h[(size_t)m*DMODEL + n] = o;
                    ushort4 u;
                    u.x=(unsigned short)f2bf(o.x); u.y=(unsigned short)f2bf(o.y);
                    u.z=(unsigned short)f2bf(o.z); u.w=(unsigned short)f2bf(o.w);
                    *(ushort4*)(hb + (size_t)m*DMODEL + n) = u;
                }
            }
        }
        gbar(cnt, gen);
    }

    // ================= stage: head (256 tiles, N=512 in two halves) ===============
    {
        const int QROWS = (SEQ - MPOS) * BATCH;  // 4096
        if (bid < QROWS/16) {
            SmemL* sm = (SmemL*)smem;
            const unsigned short* A = hb + (size_t)MPOS*BATCH*DMODEL;
            const int K = DMODEL, NS = K / BK;  // 8
            int m0 = bid * 16;
            float s = 0.f;

            #pragma unroll
            for (int nh = 0; nh < 2; ++nh) {
                f32x4 acc[4];
                #pragma unroll
                for (int j = 0; j < 4; ++j) acc[j] = (f32x4){0.f,0.f,0.f,0.f};

                const unsigned short* ga = A + (size_t)(m0 + l4)*K + c8;
                const unsigned short* gb = Wh1 + (size_t)(nh*256 + w*64 + l4)*K + c8;

                #pragma unroll
                for (int pb = 0; pb < 2; ++pb) {
                    int k = pb * BK;
                    if (w == 0) gload16(ga + k, &sm->As[pb][0][0]);
                    #pragma unroll
                    for (int rr = 0; rr < 4; ++rr)
                        gload16(gb + k + (size_t)(rr*16)*K, &sm->Bs[pb][w*64 + rr*16][0]);
                }
                for (int s2 = 0; s2 < NS; ++s2) {
                    int cur = s2 & 1;
                    if (s2 == NS - 1) { VMWAIT(0); }
                    else if (w == 0)  { VMWAIT(5); }
                    else              { VMWAIT(4); }
                    pipe_barrier();
                    bf16x8 af = *(const bf16x8*)&sm->As[cur][col][quad*8];
                    #pragma unroll
                    for (int j = 0; j < 4; ++j) {
                        bf16x8 bfr = *(const bf16x8*)&sm->Bs[cur][w*64 + j*16 + col][quad*8];
                        acc[j] = __builtin_amdgcn_mfma_f32_16x16x32_bf16(bfr, af, acc[j], 0, 0, 0);
                    }
                    pipe_barrier();
                    if (s2 + 2 < NS) {
                        int k2 = (s2 + 2) * BK;
                        if (w == 0) gload16(ga + k2, &sm->As[cur][0][0]);
                        #pragma unroll
                        for (int rr = 0; rr < 4; ++rr)
                            gload16(gb + k2 + (size_t)(rr*16)*K, &sm->Bs[cur][w*64 + rr*16][0]);
                    }
                }
                #pragma unroll
                for (int j = 0; j < 4; ++j) {
                    int n = nh*256 + w*64 + j*16 + quad*4;
                    float4 b1v = *(const float4*)&head_b1[n];
                    float4 w2v = *(const float4*)&head_w2[n];
                    s += gelu_exact(acc[j][0] + b1v.x) * w2v.x;
                    s += gelu_exact(acc[j][1] + b1v.y) * w2v.y;
                    s += gelu_exact(acc[j][2] + b1v.z) * w2v.z;
                    s += gelu_exact(acc[j][3] + b1v.w) * w2v.w;
                }
            }
            s += __shfl_xor(s, 16, 64); s += __shfl_xor(s, 32, 64);
            if (quad == 0) sm->sP[w][col] = s;
            __syncthreads();
            if (tid < 16)
                out[m0 + tid] = sm->sP[0][tid] + sm->sP[1][tid] + sm->sP[2][tid] + sm->sP[3][tid] + head_b2[0];
        }
    }
}

extern "C" void kernel_launch(void* const* d_in, const int* in_sizes, int n_in,
                              void* d_out, int out_size, void* d_ws, size_t ws_size,
                              hipStream_t stream)
{
    const float* x        = (const float*)d_in[0];
    const float* y        = (const float*)d_in[1];
    const float* xenc_w   = (const float*)d_in[3];
    const float* xenc_b   = (const float*)d_in[4];
    const float* yenc_w   = (const float*)d_in[5];
    const float* yenc_b   = (const float*)d_in[6];
    const float* in_proj_w  = (const float*)d_in[7];
    const float* in_proj_b  = (const float*)d_in[8];
    const float* out_proj_w = (const float*)d_in[9];
    const float* out_proj_b = (const float*)d_in[10];
    const float* ln1_g    = (const float*)d_in[11];
    const float* ln1_b    = (const float*)d_in[12];
    const float* lin1_w   = (const float*)d_in[13];
    const float* lin1_b   = (const float*)d_in[14];
    const float* lin2_w   = (const float*)d_in[15];
    const float* lin2_b   = (const float*)d_in[16];
    const float* ln2_g    = (const float*)d_in[17];
    const float* ln2_b    = (const float*)d_in[18];
    const float* head_w1  = (const float*)d_in[19];
    const float* head_b1  = (const float*)d_in[20];
    const float* head_w2  = (const float*)d_in[21];
    const float* head_b2  = (const float*)d_in[22];
    float* out = (float*)d_out;

    // ---- workspace layout ----
    float* ws  = (float*)d_ws;
    float* h    = ws;                                           // 8 MB f32
    unsigned short* hb    = (unsigned short*)(h + (size_t)ROWS*DMODEL);
    unsigned short* ffb   = hb    + (size_t)ROWS*DMODEL;
    unsigned short* attb  = ffb   + (size_t)ROWS*DFF;
    unsigned short* Qg    = attb  + (size_t)ROWS*DMODEL;
    unsigned short* Kg    = Qg    + (size_t)BATCH*NHEAD*SEQ*DH;
    unsigned short* Vg    = Kg    + (size_t)BATCH*NHEAD*SEQ*DH;
    unsigned short* Wqkv  = Vg    + (size_t)BATCH*NHEAD*SEQ*DH;
    unsigned short* Wout  = Wqkv  + (size_t)NLAYER*3*DMODEL*DMODEL;
    unsigned short* Wl1   = Wout  + (size_t)NLAYER*DMODEL*DMODEL;
    unsigned short* Wl2   = Wl1   + (size_t)NLAYER*DFF*DMODEL;
    unsigned short* Wh1   = Wl2   + (size_t)NLAYER*DMODEL*DFF;
    unsigned short* wend  = Wh1   + (size_t)DFF*DMODEL;

    size_t bofs = (((size_t)((char*)wend - (char*)d_ws)) + 255) & ~(size_t)255;
    int* bar = (int*)((char*)d_ws + bofs);

    hipMemsetAsync(bar, 0, 256, stream);
    mega<<<NBLK, 256, 0, stream>>>(
        x, y, xenc_w, xenc_b, yenc_w, yenc_b,
        in_proj_w, in_proj_b, out_proj_w, out_proj_b,
        ln1_g, ln1_b, lin1_w, lin1_b, lin2_w, lin2_b, ln2_g, ln2_b,
        head_w1, head_b1, head_w2, head_b2,
        h, hb, ffb, attb, Qg, Kg, Vg,
        Wqkv, Wout, Wl1, Wl2, Wh1, out, bar);
}

// Round 5
// 260.090 us; speedup vs baseline: 11.4336x; 11.4336x over previous
//
#include <hip/hip_runtime.h>
#include <hip/hip_bf16.h>
#include <math.h>

// Problem constants (fixed by setup_inputs)
#define SEQ    2048
#define BATCH  4
#define XDIM   16
#define DMODEL 256
#define NHEAD  8
#define DH     32
#define DFF    512
#define NLAYER 2
#define MPOS   1024
#define ROWS   (SEQ*BATCH)   // 8192

#define ATT_SCALE 0.17677669529663687f  // 1/sqrt(32)
#define BK 32

typedef __attribute__((ext_vector_type(8))) short bf16x8;  // MFMA A/B frag
typedef __attribute__((ext_vector_type(4))) float f32x4;   // MFMA C/D frag

__device__ __forceinline__ float gelu_exact(float x) {
    return 0.5f * x * (1.0f + erff(x * 0.70710678118654752f));
}
__device__ __forceinline__ short f2bf(float f) {
    unsigned int u = __float_as_uint(f);
    u += 0x7FFFu + ((u >> 16) & 1u);
    return (short)(u >> 16);
}
__device__ __forceinline__ float bf2f(unsigned short u) {
    return __uint_as_float(((unsigned int)u) << 16);
}
__device__ __forceinline__ void gload16(const unsigned short* g, unsigned short* l) {
    __builtin_amdgcn_global_load_lds(
        (const __attribute__((address_space(1))) unsigned int*)g,
        (__attribute__((address_space(3))) unsigned int*)l, 16, 0, 0);
}
#define VMWAIT(N) asm volatile("s_waitcnt vmcnt(" #N ")" ::: "memory")
__device__ __forceinline__ void pipe_barrier() {
    __builtin_amdgcn_sched_barrier(0);
    __builtin_amdgcn_s_barrier();
    __builtin_amdgcn_sched_barrier(0);
}

// ---------------- encoder + weight casts, ONE launch --------------------------
__global__ __launch_bounds__(256) void encode_cast(
    const float* __restrict__ x, const float* __restrict__ y,
    const float* __restrict__ xw, const float* __restrict__ xb,
    const float* __restrict__ yw, const float* __restrict__ yb,
    float* __restrict__ h, unsigned short* __restrict__ hb,
    const float* __restrict__ s0, const float* __restrict__ s1,
    const float* __restrict__ s2, const float* __restrict__ s3,
    const float* __restrict__ s4,
    unsigned short* __restrict__ d0, unsigned short* __restrict__ d1,
    unsigned short* __restrict__ d2, unsigned short* __restrict__ d3,
    unsigned short* __restrict__ d4)
{
    if (blockIdx.x < ROWS) {
        int row = blockIdx.x;      // s*BATCH + b
        int d   = threadIdx.x;     // 0..255
        int s   = row / BATCH;
        __shared__ float xs[XDIM];
        __shared__ float ys;
        if (d < XDIM) xs[d] = x[(size_t)row*XDIM + d];
        if (d == 0)   ys    = y[row];
        __syncthreads();
        float acc = xb[d];
        #pragma unroll
        for (int k = 0; k < XDIM; ++k) acc = fmaf(xs[k], xw[d*XDIM + k], acc);
        if (s < MPOS) acc += ys * yw[d] + yb[d];
        h[(size_t)row*DMODEL + d]  = acc;
        hb[(size_t)row*DMODEL + d] = (unsigned short)f2bf(acc);
        return;
    }
    int i = (blockIdx.x - ROWS)*256 + threadIdx.x;
    if (i >= 147456) return;
    const float* s; unsigned short* d; int off;
    if      (i <  49152) { s = s0; d = d0; off = i; }
    else if (i <  65536) { s = s1; d = d1; off = i - 49152; }
    else if (i <  98304) { s = s2; d = d2; off = i - 65536; }
    else if (i < 131072) { s = s3; d = d3; off = i - 98304; }
    else                 { s = s4; d = d4; off = i - 131072; }
    float4 a = *(const float4*)(s + (size_t)off*8);
    float4 c = *(const float4*)(s + (size_t)off*8 + 4);
    ushort4 u0, u1;
    u0.x=(unsigned short)f2bf(a.x); u0.y=(unsigned short)f2bf(a.y);
    u0.z=(unsigned short)f2bf(a.z); u0.w=(unsigned short)f2bf(a.w);
    u1.x=(unsigned short)f2bf(c.x); u1.y=(unsigned short)f2bf(c.y);
    u1.z=(unsigned short)f2bf(c.z); u1.w=(unsigned short)f2bf(c.w);
    *(ushort4*)(d + (size_t)off*8)     = u0;
    *(ushort4*)(d + (size_t)off*8 + 4) = u1;
}

// ---------------- qkv GEMM 128x64, 3-buffer 2-deep, fused K/V re-layout ------
__global__ __launch_bounds__(256) void gemm_qkv(
    const unsigned short* __restrict__ A, const unsigned short* __restrict__ B,
    const float* __restrict__ bias,
    unsigned short* __restrict__ Qg, unsigned short* __restrict__ Kg,
    unsigned short* __restrict__ Vg, int K)
{
    __shared__ unsigned short As[3][128][BK];   // 24 KB (reused as transpose buf)
    __shared__ unsigned short Bs[3][64][BK];
    int tid  = threadIdx.x;
    int w    = tid >> 6, lane = tid & 63;
    int col  = lane & 15, quad = lane >> 4;
    int m0   = blockIdx.y * 128, n0 = blockIdx.x * 64;
    int l4   = lane >> 2, c8 = (lane & 3) * 8;

    f32x4 acc[2][4];
    #pragma unroll
    for (int i = 0; i < 2; ++i)
        #pragma unroll
        for (int j = 0; j < 4; ++j) acc[i][j] = (f32x4){0.f,0.f,0.f,0.f};

    const unsigned short* ga = A + (size_t)(m0 + w*32 + l4)*K + c8;
    const unsigned short* gb = B + (size_t)(n0 + w*16 + l4)*K + c8;

    const int NS = K / BK;
    gload16(ga,                  &As[0][w*32     ][0]);
    gload16(ga + (size_t)16*K,   &As[0][w*32 + 16][0]);
    gload16(gb,                  &Bs[0][w*16     ][0]);
    gload16(ga + BK,                  &As[1][w*32     ][0]);
    gload16(ga + BK + (size_t)16*K,   &As[1][w*32 + 16][0]);
    gload16(gb + BK,                  &Bs[1][w*16     ][0]);

    int bcur = 0;
    for (int s = 0; s < NS; ++s) {
        if (s == NS - 1) { VMWAIT(0); } else { VMWAIT(3); }
        pipe_barrier();
        if (s + 2 < NS) {
            int bpre = bcur + 2; if (bpre >= 3) bpre -= 3;
            int k2 = (s + 2) * BK;
            gload16(ga + k2,                &As[bpre][w*32     ][0]);
            gload16(ga + k2 + (size_t)16*K, &As[bpre][w*32 + 16][0]);
            gload16(gb + k2,                &Bs[bpre][w*16     ][0]);
        }
        bf16x8 af[2], bfr[4];
        #pragma unroll
        for (int i = 0; i < 2; ++i) af[i]  = *(const bf16x8*)&As[bcur][w*32 + i*16 + col][quad*8];
        #pragma unroll
        for (int j = 0; j < 4; ++j) bfr[j] = *(const bf16x8*)&Bs[bcur][j*16 + col][quad*8];
        #pragma unroll
        for (int i = 0; i < 2; ++i)
            #pragma unroll
            for (int j = 0; j < 4; ++j)
                acc[i][j] = __builtin_amdgcn_mfma_f32_16x16x32_bf16(bfr[j], af[i], acc[i][j], 0, 0, 0);
        bcur = (bcur == 2) ? 0 : bcur + 1;
    }

    int region = n0 >> 8;   // 0=Q, 1=K, 2=V (uniform per block)
    if (region < 2) {
        #pragma unroll
        for (int i = 0; i < 2; ++i) {
            int m = m0 + w*32 + i*16 + col;
            int s = m >> 2, bidx = m & 3;
            #pragma unroll
            for (int j = 0; j < 4; ++j) {
                int ng = n0 + j*16 + quad*4;
                float4 bi = *(const float4*)&bias[ng];
                ushort4 u;
                u.x=(unsigned short)f2bf(acc[i][j][0] + bi.x);
                u.y=(unsigned short)f2bf(acc[i][j][1] + bi.y);
                u.z=(unsigned short)f2bf(acc[i][j][2] + bi.z);
                u.w=(unsigned short)f2bf(acc[i][j][3] + bi.w);
                int np = ng - (region << 8);
                int hh = np >> 5, d = np & 31;
                int bh = bidx*NHEAD + hh;
                if (region == 0)
                    *(ushort4*)(Qg + ((size_t)(bh*SEQ + s))*DH + d) = u;
                else
                    *(ushort4*)(Kg + ((size_t)(bh*SEQ + s))*DH + d) = u;
            }
        }
    } else {
        __syncthreads();   // all waves done reading As before aliasing it
        unsigned short* T3 = (unsigned short*)As;   // 16 KB needed <= 24 KB
        #pragma unroll
        for (int i = 0; i < 2; ++i) {
            int mi = w*32 + i*16 + col;
            int ss = mi >> 2, bidx = mi & 3;
            #pragma unroll
            for (int j = 0; j < 4; ++j) {
                int ni = j*16 + quad*4;
                float4 bi = *(const float4*)&bias[n0 + ni];
                T3[((ni    )*4 + bidx)*32 + ss] = (unsigned short)f2bf(acc[i][j][0] + bi.x);
                T3[((ni + 1)*4 + bidx)*32 + ss] = (unsigned short)f2bf(acc[i][j][1] + bi.y);
                T3[((ni + 2)*4 + bidx)*32 + ss] = (unsigned short)f2bf(acc[i][j][2] + bi.z);
                T3[((ni + 3)*4 + bidx)*32 + ss] = (unsigned short)f2bf(acc[i][j][3] + bi.w);
            }
        }
        __syncthreads();
        int sBase = m0 >> 2;
        #pragma unroll
        for (int r = 0; r < 4; ++r) {
            int chunk = tid + 256*r;
            int l = chunk >> 2, p = chunk & 3;
            int d = l & 31, hh_l = (l >> 5) & 1, bidx = l >> 6;
            int ni = hh_l*32 + d;
            int hh = ((n0 & 255) + ni) >> 5;
            int bh = bidx*NHEAD + hh;
            uint4 val = *(const uint4*)&T3[(ni*4 + bidx)*32 + p*8];
            *(uint4*)(Vg + ((size_t)(bh*DH + d))*SEQ + sBase + p*8) = val;
        }
    }
}

// ---------------- MFMA flash attention, transposed flow ----------------------
__global__ __launch_bounds__(256) void attn_mfma(
    const unsigned short* __restrict__ Qg,
    const unsigned short* __restrict__ Kg,
    const unsigned short* __restrict__ Vg,
    unsigned short* __restrict__ o)           // bf16 [s*B+b][256]
{
    const int id = blockIdx.x;                // 0..1023
    const int sl = id >> 3;
    const int bh = (id & 7) * 4 + (sl >> 5);  // XCD (id&7) gets bh in [4x, 4x+4)
    const int qt = sl & 31;
    const int h  = bh & 7;
    const int b  = bh >> 3;
    const int q0 = qt * 64;
    const int tid  = threadIdx.x;
    const int w    = tid >> 6;
    const int lane = tid & 63;
    const int col  = lane & 15;
    const int quad = lane >> 4;

    __shared__ unsigned short Kt[2][64][40];  // [key][d]
    __shared__ unsigned short Vt[2][32][72];  // [d][key]
    __shared__ unsigned short Pt[4][16][72];  // per-wave P [q][key]

    const int q = q0 + 16*w + col;
    bf16x8 qf = *(const bf16x8*)(Qg + ((size_t)(bh*SEQ + q))*DH + quad*8);

    f32x4 O0 = {0.f,0.f,0.f,0.f};
    f32x4 O1 = {0.f,0.f,0.f,0.f};
    float lsum = 0.f;

    const int kRow = tid >> 2, kCh = (tid & 3) * 8;
    const int vD   = tid >> 3, vCh = (tid & 7) * 8;

    const int nT = 16 + ((q0 >= MPOS) ? 1 : 0);
    uint4 kreg = *(const uint4*)(Kg + ((size_t)(bh*SEQ + kRow))*DH + kCh);
    uint4 vreg = *(const uint4*)(Vg + ((size_t)(bh*DH + vD))*SEQ + vCh);

    for (int kt = 0; kt < nT; ++kt) {
        const bool self = (kt == 16);
        const int  p    = kt & 1;
        *(uint4*)&Kt[p][kRow][kCh] = kreg;
        *(uint4*)&Vt[p][vD][vCh]   = vreg;
        __syncthreads();
        if (kt + 1 < nT) {
            int kn = (kt + 1 == 16) ? q0 : (kt + 1)*64;
            kreg = *(const uint4*)(Kg + ((size_t)(bh*SEQ + kn + kRow))*DH + kCh);
            vreg = *(const uint4*)(Vg + ((size_t)(bh*DH + vD))*SEQ + kn + vCh);
        }

        #pragma unroll
        for (int mt = 0; mt < 4; ++mt) {
            bf16x8 kf = *(const bf16x8*)&Kt[p][mt*16 + col][quad*8];
            f32x4 st = {0.f,0.f,0.f,0.f};
            st = __builtin_amdgcn_mfma_f32_16x16x32_bf16(kf, qf, st, 0, 0, 0);
            ushort4 pw;
            #pragma unroll
            for (int i = 0; i < 4; ++i) {
                float pv = __expf(st[i]*ATT_SCALE);
                if (self && (mt*16 + quad*4 + i != 16*w + col)) pv = 0.f;
                unsigned short us = (unsigned short)f2bf(pv);
                ((unsigned short*)&pw)[i] = us;
                lsum += bf2f(us);
            }
            *(ushort4*)&Pt[w][col][mt*16 + quad*4] = pw;
        }
        #pragma unroll
        for (int c = 0; c < 2; ++c) {
            bf16x8 pf = *(const bf16x8*)&Pt[w][col][c*32 + quad*8];
            bf16x8 v0 = *(const bf16x8*)&Vt[p][col     ][c*32 + quad*8];
            bf16x8 v1 = *(const bf16x8*)&Vt[p][col + 16][c*32 + quad*8];
            O0 = __builtin_amdgcn_mfma_f32_16x16x32_bf16(v0, pf, O0, 0, 0, 0);
            O1 = __builtin_amdgcn_mfma_f32_16x16x32_bf16(v1, pf, O1, 0, 0, 0);
        }
    }

    lsum += __shfl_xor(lsum, 16, 64);
    lsum += __shfl_xor(lsum, 32, 64);
    float inv = 1.0f / lsum;
    ushort4 u0, u1;
    #pragma unroll
    for (int i = 0; i < 4; ++i) {
        ((unsigned short*)&u0)[i] = (unsigned short)f2bf(O0[i]*inv);
        ((unsigned short*)&u1)[i] = (unsigned short)f2bf(O1[i]*inv);
    }
    unsigned short* op = o + ((size_t)(q*BATCH + b))*DMODEL + h*DH;
    *(ushort4*)(op + quad*4)      = u0;
    *(ushort4*)(op + 16 + quad*4) = u1;
}

// ---------------- fused MLP: out-proj + LN1 + ff1 + gelu + ff2 + LN2 (+head) --
// Row-local fusion: block owns 16 rows end-to-end. A-operands for ff1/ff2/head
// come from LDS tiles (LN1 out / gelu out / LN2 out) - no global round-trips.
// Grid 512, m0 interleaves low/high rows so head-carrying blocks spread evenly.
__global__ __launch_bounds__(256, 2) void mlp_fused(
    const unsigned short* __restrict__ attb,
    const unsigned short* __restrict__ Wout, const float* __restrict__ ob,
    const float* __restrict__ g1, const float* __restrict__ be1,
    const unsigned short* __restrict__ W1, const float* __restrict__ fb1,
    const unsigned short* __restrict__ W2, const float* __restrict__ fb2,
    const float* __restrict__ g2, const float* __restrict__ be2,
    float* __restrict__ h, unsigned short* __restrict__ hb,
    const unsigned short* __restrict__ Wh1, const float* __restrict__ hb1,
    const float* __restrict__ hw2, const float* __restrict__ hb2,
    float* __restrict__ out, int doHead)
{
    __shared__ unsigned short Bs[3][256][BK];   // 48 KB weight staging
    __shared__ unsigned short As[3][16][BK];    // 3 KB  activation staging (stage A)
    __shared__ unsigned short Ht[16][264];      // LN1-out (later LN2-out) bf16, padded
    __shared__ unsigned short Pt[16][520];      // gelu(ff1) bf16, padded
    __shared__ float sP[4][16], qP[4][16];

    const int tid  = threadIdx.x;
    const int w    = tid >> 6;
    const int lane = tid & 63;
    const int col  = lane & 15;
    const int quad = lane >> 4;
    const int l4   = lane >> 2;
    const int c8   = (lane & 3) * 8;
    const int bid  = blockIdx.x;
    const int m0   = ((bid >> 1) * 16) + ((bid & 1) * 4096);
    const int m    = m0 + col;

    float resid[4][4];   // LN1 output (h'), residual for stage C

    // ================= stage A: out-proj (K=256) + residual + LN1 =============
    {
        f32x4 acc[4];
        #pragma unroll
        for (int j = 0; j < 4; ++j) acc[j] = (f32x4){0.f,0.f,0.f,0.f};

        const unsigned short* ga = attb + (size_t)(m0 + l4)*DMODEL + c8;
        const unsigned short* gb = Wout + (size_t)(w*64 + l4)*DMODEL + c8;
        const int NS = DMODEL / BK;  // 8

        #pragma unroll
        for (int pb = 0; pb < 2; ++pb) {
            int k = pb * BK;
            if (w == 0) gload16(ga + k, &As[pb][0][0]);
            #pragma unroll
            for (int rr = 0; rr < 4; ++rr)
                gload16(gb + k + (size_t)(rr*16)*DMODEL, &Bs[pb][w*64 + rr*16][0]);
        }
        int bcur = 0;
        for (int s = 0; s < NS; ++s) {
            if (s == NS - 1)  { VMWAIT(0); }
            else if (w == 0)  { VMWAIT(5); }
            else              { VMWAIT(4); }
            pipe_barrier();
            if (s + 2 < NS) {
                int bpre = bcur + 2; if (bpre >= 3) bpre -= 3;
                int k2 = (s + 2) * BK;
                if (w == 0) gload16(ga + k2, &As[bpre][0][0]);
                #pragma unroll
                for (int rr = 0; rr < 4; ++rr)
                    gload16(gb + k2 + (size_t)(rr*16)*DMODEL, &Bs[bpre][w*64 + rr*16][0]);
            }
            bf16x8 af = *(const bf16x8*)&As[bcur][col][quad*8];
            #pragma unroll
            for (int j = 0; j < 4; ++j) {
                bf16x8 bfr = *(const bf16x8*)&Bs[bcur][w*64 + j*16 + col][quad*8];
                acc[j] = __builtin_amdgcn_mfma_f32_16x16x32_bf16(bfr, af, acc[j], 0, 0, 0);
            }
            bcur = (bcur == 2) ? 0 : bcur + 1;
        }

        float s = 0.f, q = 0.f;
        #pragma unroll
        for (int j = 0; j < 4; ++j) {
            int n = w*64 + j*16 + quad*4;
            float4 bi = *(const float4*)&ob[n];
            float4 hv = *(const float4*)&h[(size_t)m*DMODEL + n];
            #pragma unroll
            for (int i = 0; i < 4; ++i) {
                float val = acc[j][i] + ((const float*)&bi)[i] + ((const float*)&hv)[i];
                resid[j][i] = val;
                s += val; q += val*val;
            }
        }
        s += __shfl_xor(s, 16, 64); s += __shfl_xor(s, 32, 64);
        q += __shfl_xor(q, 16, 64); q += __shfl_xor(q, 32, 64);
        if (quad == 0) { sP[w][col] = s; qP[w][col] = q; }
        __syncthreads();
        float st = sP[0][col] + sP[1][col] + sP[2][col] + sP[3][col];
        float qt = qP[0][col] + qP[1][col] + qP[2][col] + qP[3][col];
        float mu   = st * (1.0f/DMODEL);
        float var  = qt * (1.0f/DMODEL) - mu*mu;
        float rstd = rsqrtf(var + 1e-5f);
        #pragma unroll
        for (int j = 0; j < 4; ++j) {
            int n = w*64 + j*16 + quad*4;
            float4 gv = *(const float4*)&g1[n];
            float4 bv = *(const float4*)&be1[n];
            ushort4 u;
            #pragma unroll
            for (int i = 0; i < 4; ++i) {
                float o = (resid[j][i]-mu)*rstd*((const float*)&gv)[i] + ((const float*)&bv)[i];
                resid[j][i] = o;            // h' (LN1 out) stays in regs
                ((unsigned short*)&u)[i] = (unsigned short)f2bf(o);
            }
            *(ushort4*)&Ht[col][n] = u;     // bf16 A-operand for ff1
        }
        __syncthreads();                    // Ht visible to all waves
    }

    // ================= stage B: ff1 (K=256, N=512 in two halves) + gelu =======
    #pragma unroll 1
    for (int nh = 0; nh < 2; ++nh) {
        f32x4 acc[4];
        #pragma unroll
        for (int j = 0; j < 4; ++j) acc[j] = (f32x4){0.f,0.f,0.f,0.f};
        const unsigned short* gb = W1 + (size_t)(nh*256 + w*64 + l4)*DMODEL + c8;
        const int NS = DMODEL / BK;  // 8

        #pragma unroll
        for (int pb = 0; pb < 2; ++pb)
            #pragma unroll
            for (int rr = 0; rr < 4; ++rr)
                gload16(gb + pb*BK + (size_t)(rr*16)*DMODEL, &Bs[pb][w*64 + rr*16][0]);

        int bcur = 0;
        for (int s = 0; s < NS; ++s) {
            if (s == NS - 1) { VMWAIT(0); } else { VMWAIT(4); }
            pipe_barrier();
            if (s + 2 < NS) {
                int bpre = bcur + 2; if (bpre >= 3) bpre -= 3;
                int k2 = (s + 2) * BK;
                #pragma unroll
                for (int rr = 0; rr < 4; ++rr)
                    gload16(gb + k2 + (size_t)(rr*16)*DMODEL, &Bs[bpre][w*64 + rr*16][0]);
            }
            bf16x8 af = *(const bf16x8*)&Ht[col][s*BK + quad*8];
            #pragma unroll
            for (int j = 0; j < 4; ++j) {
                bf16x8 bfr = *(const bf16x8*)&Bs[bcur][w*64 + j*16 + col][quad*8];
                acc[j] = __builtin_amdgcn_mfma_f32_16x16x32_bf16(bfr, af, acc[j], 0, 0, 0);
            }
            bcur = (bcur == 2) ? 0 : bcur + 1;
        }
        #pragma unroll
        for (int j = 0; j < 4; ++j) {
            int n2 = nh*256 + w*64 + j*16 + quad*4;
            float4 bi = *(const float4*)&fb1[n2];
            ushort4 u;
            #pragma unroll
            for (int i = 0; i < 4; ++i)
                ((unsigned short*)&u)[i] = (unsigned short)f2bf(gelu_exact(acc[j][i] + ((const float*)&bi)[i]));
            *(ushort4*)&Pt[col][n2] = u;
        }
        pipe_barrier();   // all waves past Bs reads before next half's staging
    }

    // ================= stage C: ff2 (K=512) + residual + LN2 ==================
    {
        __syncthreads();  // Pt visible
        f32x4 acc[4];
        #pragma unroll
        for (int j = 0; j < 4; ++j) acc[j] = (f32x4){0.f,0.f,0.f,0.f};
        const unsigned short* gb = W2 + (size_t)(w*64 + l4)*DFF + c8;
        const int NS = DFF / BK;  // 16

        #pragma unroll
        for (int pb = 0; pb < 2; ++pb)
            #pragma unroll
            for (int rr = 0; rr < 4; ++rr)
                gload16(gb + pb*BK + (size_t)(rr*16)*DFF, &Bs[pb][w*64 + rr*16][0]);

        int bcur = 0;
        for (int s = 0; s < NS; ++s) {
            if (s == NS - 1) { VMWAIT(0); } else { VMWAIT(4); }
            pipe_barrier();
            if (s + 2 < NS) {
                int bpre = bcur + 2; if (bpre >= 3) bpre -= 3;
                int k2 = (s + 2) * BK;
                #pragma unroll
                for (int rr = 0; rr < 4; ++rr)
                    gload16(gb + k2 + (size_t)(rr*16)*DFF, &Bs[bpre][w*64 + rr*16][0]);
            }
            bf16x8 af = *(const bf16x8*)&Pt[col][s*BK + quad*8];
            #pragma unroll
            for (int j = 0; j < 4; ++j) {
                bf16x8 bfr = *(const bf16x8*)&Bs[bcur][w*64 + j*16 + col][quad*8];
                acc[j] = __builtin_amdgcn_mfma_f32_16x16x32_bf16(bfr, af, acc[j], 0, 0, 0);
            }
            bcur = (bcur == 2) ? 0 : bcur + 1;
        }

        float s = 0.f, q = 0.f;
        float v[4][4];
        #pragma unroll
        for (int j = 0; j < 4; ++j) {
            int n = w*64 + j*16 + quad*4;
            float4 bi = *(const float4*)&fb2[n];
            #pragma unroll
            for (int i = 0; i < 4; ++i) {
                float val = acc[j][i] + ((const float*)&bi)[i] + resid[j][i];
                v[j][i] = val;
                s += val; q += val*val;
            }
        }
        s += __shfl_xor(s, 16, 64); s += __shfl_xor(s, 32, 64);
        q += __shfl_xor(q, 16, 64); q += __shfl_xor(q, 32, 64);
        if (quad == 0) { sP[w][col] = s; qP[w][col] = q; }
        __syncthreads();
        float st = sP[0][col] + sP[1][col] + sP[2][col] + sP[3][col];
        float qt = qP[0][col] + qP[1][col] + qP[2][col] + qP[3][col];
        float mu   = st * (1.0f/DMODEL);
        float var  = qt * (1.0f/DMODEL) - mu*mu;
        float rstd = rsqrtf(var + 1e-5f);
        #pragma unroll
        for (int j = 0; j < 4; ++j) {
            int n = w*64 + j*16 + quad*4;
            float4 gv = *(const float4*)&g2[n];
            float4 bv = *(const float4*)&be2[n];
            float4 o;
            ushort4 u;
            #pragma unroll
            for (int i = 0; i < 4; ++i) {
                float ov = (v[j][i]-mu)*rstd*((const float*)&gv)[i] + ((const float*)&bv)[i];
                ((float*)&o)[i] = ov;
                ((unsigned short*)&u)[i] = (unsigned short)f2bf(ov);
            }
            *(float4*)&h[(size_t)m*DMODEL + n] = o;
            *(ushort4*)(hb + (size_t)m*DMODEL + n) = u;
            *(ushort4*)&Ht[col][n] = u;     // LN2 bf16 for head
        }
        __syncthreads();
    }

    // ================= stage D: head (layer 1, rows >= MPOS only) =============
    if (doHead && m0 >= 4096) {
        float sdot = 0.f;
        #pragma unroll 1
        for (int nh = 0; nh < 2; ++nh) {
            f32x4 acc[4];
            #pragma unroll
            for (int j = 0; j < 4; ++j) acc[j] = (f32x4){0.f,0.f,0.f,0.f};
            const unsigned short* gb = Wh1 + (size_t)(nh*256 + w*64 + l4)*DMODEL + c8;
            const int NS = DMODEL / BK;  // 8

            #pragma unroll
            for (int pb = 0; pb < 2; ++pb)
                #pragma unroll
                for (int rr = 0; rr < 4; ++rr)
                    gload16(gb + pb*BK + (size_t)(rr*16)*DMODEL, &Bs[pb][w*64 + rr*16][0]);

            int bcur = 0;
            for (int s = 0; s < NS; ++s) {
                if (s == NS - 1) { VMWAIT(0); } else { VMWAIT(4); }
                pipe_barrier();
                if (s + 2 < NS) {
                    int bpre = bcur + 2; if (bpre >= 3) bpre -= 3;
                    int k2 = (s + 2) * BK;
                    #pragma unroll
                    for (int rr = 0; rr < 4; ++rr)
                        gload16(gb + k2 + (size_t)(rr*16)*DMODEL, &Bs[bpre][w*64 + rr*16][0]);
                }
                bf16x8 af = *(const bf16x8*)&Ht[col][s*BK + quad*8];
                #pragma unroll
                for (int j = 0; j < 4; ++j) {
                    bf16x8 bfr = *(const bf16x8*)&Bs[bcur][w*64 + j*16 + col][quad*8];
                    acc[j] = __builtin_amdgcn_mfma_f32_16x16x32_bf16(bfr, af, acc[j], 0, 0, 0);
                }
                bcur = (bcur == 2) ? 0 : bcur + 1;
            }
            #pragma unroll
            for (int j = 0; j < 4; ++j) {
                int n2 = nh*256 + w*64 + j*16 + quad*4;
                float4 b1v = *(const float4*)&hb1[n2];
                float4 w2v = *(const float4*)&hw2[n2];
                #pragma unroll
                for (int i = 0; i < 4; ++i)
                    sdot += gelu_exact(acc[j][i] + ((const float*)&b1v)[i]) * ((const float*)&w2v)[i];
            }
            pipe_barrier();
        }
        sdot += __shfl_xor(sdot, 16, 64); sdot += __shfl_xor(sdot, 32, 64);
        if (quad == 0) sP[w][col] = sdot;
        __syncthreads();
        if (tid < 16)
            out[(m0 - 4096) + tid] = sP[0][tid] + sP[1][tid] + sP[2][tid] + sP[3][tid] + hb2[0];
    }
}

extern "C" void kernel_launch(void* const* d_in, const int* in_sizes, int n_in,
                              void* d_out, int out_size, void* d_ws, size_t ws_size,
                              hipStream_t stream)
{
    const float* x        = (const float*)d_in[0];
    const float* y        = (const float*)d_in[1];
    const float* xenc_w   = (const float*)d_in[3];
    const float* xenc_b   = (const float*)d_in[4];
    const float* yenc_w   = (const float*)d_in[5];
    const float* yenc_b   = (const float*)d_in[6];
    const float* in_proj_w  = (const float*)d_in[7];
    const float* in_proj_b  = (const float*)d_in[8];
    const float* out_proj_w = (const float*)d_in[9];
    const float* out_proj_b = (const float*)d_in[10];
    const float* ln1_g    = (const float*)d_in[11];
    const float* ln1_b    = (const float*)d_in[12];
    const float* lin1_w   = (const float*)d_in[13];
    const float* lin1_b   = (const float*)d_in[14];
    const float* lin2_w   = (const float*)d_in[15];
    const float* lin2_b   = (const float*)d_in[16];
    const float* ln2_g    = (const float*)d_in[17];
    const float* ln2_b    = (const float*)d_in[18];
    const float* head_w1  = (const float*)d_in[19];
    const float* head_b1  = (const float*)d_in[20];
    const float* head_w2  = (const float*)d_in[21];
    const float* head_b2  = (const float*)d_in[22];
    float* out = (float*)d_out;

    // ---- workspace layout ----
    float* ws  = (float*)d_ws;
    float* h    = ws;                                           // 8 MB f32
    unsigned short* hb    = (unsigned short*)(h + (size_t)ROWS*DMODEL);
    unsigned short* attb  = hb    + (size_t)ROWS*DMODEL;
    unsigned short* Qg    = attb  + (size_t)ROWS*DMODEL;
    unsigned short* Kg    = Qg    + (size_t)BATCH*NHEAD*SEQ*DH;
    unsigned short* Vg    = Kg    + (size_t)BATCH*NHEAD*SEQ*DH;
    unsigned short* Wqkv  = Vg    + (size_t)BATCH*NHEAD*SEQ*DH;
    unsigned short* Wout  = Wqkv  + (size_t)NLAYER*3*DMODEL*DMODEL;
    unsigned short* Wl1   = Wout  + (size_t)NLAYER*DMODEL*DMODEL;
    unsigned short* Wl2   = Wl1   + (size_t)NLAYER*DFF*DMODEL;
    unsigned short* Wh1   = Wl2   + (size_t)NLAYER*DMODEL*DFF;

    encode_cast<<<ROWS + 576, 256, 0, stream>>>(
        x, y, xenc_w, xenc_b, yenc_w, yenc_b, h, hb,
        in_proj_w, out_proj_w, lin1_w, lin2_w, head_w1,
        Wqkv, Wout, Wl1, Wl2, Wh1);

    for (int l = 0; l < NLAYER; ++l) {
        gemm_qkv<<<dim3(12, ROWS/128), 256, 0, stream>>>(
            hb, Wqkv + (size_t)l*3*DMODEL*DMODEL, in_proj_b + l*3*DMODEL,
            Qg, Kg, Vg, DMODEL);
        attn_mfma<<<dim3(SEQ/64 * NHEAD * BATCH), 256, 0, stream>>>(Qg, Kg, Vg, attb);
        mlp_fused<<<ROWS/16, 256, 0, stream>>>(
            attb,
            Wout + (size_t)l*DMODEL*DMODEL, out_proj_b + l*DMODEL,
            ln1_g + l*DMODEL, ln1_b + l*DMODEL,
            Wl1 + (size_t)l*DFF*DMODEL, lin1_b + l*DFF,
            Wl2 + (size_t)l*DMODEL*DFF, lin2_b + l*DMODEL,
            ln2_g + l*DMODEL, ln2_b + l*DMODEL,
            h, hb,
            Wh1, head_b1, head_w2, head_b2,
            out, (l == NLAYER-1) ? 1 : 0);
    }
}

// Round 6
// 258.411 us; speedup vs baseline: 11.5079x; 1.0065x over previous
//
#include <hip/hip_runtime.h>
#include <hip/hip_bf16.h>
#include <math.h>

// Problem constants (fixed by setup_inputs)
#define SEQ    2048
#define BATCH  4
#define XDIM   16
#define DMODEL 256
#define NHEAD  8
#define DH     32
#define DFF    512
#define NLAYER 2
#define MPOS   1024
#define ROWS   (SEQ*BATCH)   // 8192

#define ATT_SCALE 0.17677669529663687f  // 1/sqrt(32)
#define BK 32

typedef __attribute__((ext_vector_type(8))) short bf16x8;  // MFMA A/B frag
typedef __attribute__((ext_vector_type(4))) float f32x4;   // MFMA C/D frag

__device__ __forceinline__ float gelu_exact(float x) {
    return 0.5f * x * (1.0f + erff(x * 0.70710678118654752f));
}
__device__ __forceinline__ short f2bf(float f) {
    unsigned int u = __float_as_uint(f);
    u += 0x7FFFu + ((u >> 16) & 1u);
    return (short)(u >> 16);
}
__device__ __forceinline__ float bf2f(unsigned short u) {
    return __uint_as_float(((unsigned int)u) << 16);
}
__device__ __forceinline__ void gload16(const unsigned short* g, unsigned short* l) {
    __builtin_amdgcn_global_load_lds(
        (const __attribute__((address_space(1))) unsigned int*)g,
        (__attribute__((address_space(3))) unsigned int*)l, 16, 0, 0);
}
#define VMWAIT(N) asm volatile("s_waitcnt vmcnt(" #N ")" ::: "memory")
__device__ __forceinline__ void pipe_barrier() {
    __builtin_amdgcn_sched_barrier(0);
    __builtin_amdgcn_s_barrier();
    __builtin_amdgcn_sched_barrier(0);
}

// ---------------- encoder + weight casts, ONE launch --------------------------
__global__ __launch_bounds__(256) void encode_cast(
    const float* __restrict__ x, const float* __restrict__ y,
    const float* __restrict__ xw, const float* __restrict__ xb,
    const float* __restrict__ yw, const float* __restrict__ yb,
    float* __restrict__ h, unsigned short* __restrict__ hb,
    const float* __restrict__ s0, const float* __restrict__ s1,
    const float* __restrict__ s2, const float* __restrict__ s3,
    const float* __restrict__ s4,
    unsigned short* __restrict__ d0, unsigned short* __restrict__ d1,
    unsigned short* __restrict__ d2, unsigned short* __restrict__ d3,
    unsigned short* __restrict__ d4)
{
    if (blockIdx.x < ROWS) {
        int row = blockIdx.x;      // s*BATCH + b
        int d   = threadIdx.x;     // 0..255
        int s   = row / BATCH;
        __shared__ float xs[XDIM];
        __shared__ float ys;
        if (d < XDIM) xs[d] = x[(size_t)row*XDIM + d];
        if (d == 0)   ys    = y[row];
        __syncthreads();
        float acc = xb[d];
        #pragma unroll
        for (int k = 0; k < XDIM; ++k) acc = fmaf(xs[k], xw[d*XDIM + k], acc);
        if (s < MPOS) acc += ys * yw[d] + yb[d];
        h[(size_t)row*DMODEL + d]  = acc;
        hb[(size_t)row*DMODEL + d] = (unsigned short)f2bf(acc);
        return;
    }
    int i = (blockIdx.x - ROWS)*256 + threadIdx.x;
    if (i >= 147456) return;
    const float* s; unsigned short* d; int off;
    if      (i <  49152) { s = s0; d = d0; off = i; }
    else if (i <  65536) { s = s1; d = d1; off = i - 49152; }
    else if (i <  98304) { s = s2; d = d2; off = i - 65536; }
    else if (i < 131072) { s = s3; d = d3; off = i - 98304; }
    else                 { s = s4; d = d4; off = i - 131072; }
    float4 a = *(const float4*)(s + (size_t)off*8);
    float4 c = *(const float4*)(s + (size_t)off*8 + 4);
    ushort4 u0, u1;
    u0.x=(unsigned short)f2bf(a.x); u0.y=(unsigned short)f2bf(a.y);
    u0.z=(unsigned short)f2bf(a.z); u0.w=(unsigned short)f2bf(a.w);
    u1.x=(unsigned short)f2bf(c.x); u1.y=(unsigned short)f2bf(c.y);
    u1.z=(unsigned short)f2bf(c.z); u1.w=(unsigned short)f2bf(c.w);
    *(ushort4*)(d + (size_t)off*8)     = u0;
    *(ushort4*)(d + (size_t)off*8 + 4) = u1;
}

// ---------------- qkv GEMM 128x64, 3-buffer 2-deep, fused K/V re-layout ------
__global__ __launch_bounds__(256) void gemm_qkv(
    const unsigned short* __restrict__ A, const unsigned short* __restrict__ B,
    const float* __restrict__ bias,
    unsigned short* __restrict__ Qg, unsigned short* __restrict__ Kg,
    unsigned short* __restrict__ Vg, int K)
{
    __shared__ unsigned short As[3][128][BK];   // 24 KB (reused as transpose buf)
    __shared__ unsigned short Bs[3][64][BK];
    int tid  = threadIdx.x;
    int w    = tid >> 6, lane = tid & 63;
    int col  = lane & 15, quad = lane >> 4;
    int m0   = blockIdx.y * 128, n0 = blockIdx.x * 64;
    int l4   = lane >> 2, c8 = (lane & 3) * 8;

    f32x4 acc[2][4];
    #pragma unroll
    for (int i = 0; i < 2; ++i)
        #pragma unroll
        for (int j = 0; j < 4; ++j) acc[i][j] = (f32x4){0.f,0.f,0.f,0.f};

    const unsigned short* ga = A + (size_t)(m0 + w*32 + l4)*K + c8;
    const unsigned short* gb = B + (size_t)(n0 + w*16 + l4)*K + c8;

    const int NS = K / BK;
    gload16(ga,                  &As[0][w*32     ][0]);
    gload16(ga + (size_t)16*K,   &As[0][w*32 + 16][0]);
    gload16(gb,                  &Bs[0][w*16     ][0]);
    gload16(ga + BK,                  &As[1][w*32     ][0]);
    gload16(ga + BK + (size_t)16*K,   &As[1][w*32 + 16][0]);
    gload16(gb + BK,                  &Bs[1][w*16     ][0]);

    int bcur = 0;
    for (int s = 0; s < NS; ++s) {
        if (s == NS - 1) { VMWAIT(0); } else { VMWAIT(3); }
        pipe_barrier();
        if (s + 2 < NS) {
            int bpre = bcur + 2; if (bpre >= 3) bpre -= 3;
            int k2 = (s + 2) * BK;
            gload16(ga + k2,                &As[bpre][w*32     ][0]);
            gload16(ga + k2 + (size_t)16*K, &As[bpre][w*32 + 16][0]);
            gload16(gb + k2,                &Bs[bpre][w*16     ][0]);
        }
        bf16x8 af[2], bfr[4];
        #pragma unroll
        for (int i = 0; i < 2; ++i) af[i]  = *(const bf16x8*)&As[bcur][w*32 + i*16 + col][quad*8];
        #pragma unroll
        for (int j = 0; j < 4; ++j) bfr[j] = *(const bf16x8*)&Bs[bcur][j*16 + col][quad*8];
        #pragma unroll
        for (int i = 0; i < 2; ++i)
            #pragma unroll
            for (int j = 0; j < 4; ++j)
                acc[i][j] = __builtin_amdgcn_mfma_f32_16x16x32_bf16(bfr[j], af[i], acc[i][j], 0, 0, 0);
        bcur = (bcur == 2) ? 0 : bcur + 1;
    }

    int region = n0 >> 8;   // 0=Q, 1=K, 2=V (uniform per block)
    if (region < 2) {
        #pragma unroll
        for (int i = 0; i < 2; ++i) {
            int m = m0 + w*32 + i*16 + col;
            int s = m >> 2, bidx = m & 3;
            #pragma unroll
            for (int j = 0; j < 4; ++j) {
                int ng = n0 + j*16 + quad*4;
                float4 bi = *(const float4*)&bias[ng];
                ushort4 u;
                u.x=(unsigned short)f2bf(acc[i][j][0] + bi.x);
                u.y=(unsigned short)f2bf(acc[i][j][1] + bi.y);
                u.z=(unsigned short)f2bf(acc[i][j][2] + bi.z);
                u.w=(unsigned short)f2bf(acc[i][j][3] + bi.w);
                int np = ng - (region << 8);
                int hh = np >> 5, d = np & 31;
                int bh = bidx*NHEAD + hh;
                if (region == 0)
                    *(ushort4*)(Qg + ((size_t)(bh*SEQ + s))*DH + d) = u;
                else
                    *(ushort4*)(Kg + ((size_t)(bh*SEQ + s))*DH + d) = u;
            }
        }
    } else {
        __syncthreads();   // all waves done reading As before aliasing it
        unsigned short* T3 = (unsigned short*)As;   // 16 KB needed <= 24 KB
        #pragma unroll
        for (int i = 0; i < 2; ++i) {
            int mi = w*32 + i*16 + col;
            int ss = mi >> 2, bidx = mi & 3;
            #pragma unroll
            for (int j = 0; j < 4; ++j) {
                int ni = j*16 + quad*4;
                float4 bi = *(const float4*)&bias[n0 + ni];
                T3[((ni    )*4 + bidx)*32 + ss] = (unsigned short)f2bf(acc[i][j][0] + bi.x);
                T3[((ni + 1)*4 + bidx)*32 + ss] = (unsigned short)f2bf(acc[i][j][1] + bi.y);
                T3[((ni + 2)*4 + bidx)*32 + ss] = (unsigned short)f2bf(acc[i][j][2] + bi.z);
                T3[((ni + 3)*4 + bidx)*32 + ss] = (unsigned short)f2bf(acc[i][j][3] + bi.w);
            }
        }
        __syncthreads();
        int sBase = m0 >> 2;
        #pragma unroll
        for (int r = 0; r < 4; ++r) {
            int chunk = tid + 256*r;
            int l = chunk >> 2, p = chunk & 3;
            int d = l & 31, hh_l = (l >> 5) & 1, bidx = l >> 6;
            int ni = hh_l*32 + d;
            int hh = ((n0 & 255) + ni) >> 5;
            int bh = bidx*NHEAD + hh;
            uint4 val = *(const uint4*)&T3[(ni*4 + bidx)*32 + p*8];
            *(uint4*)(Vg + ((size_t)(bh*DH + d))*SEQ + sBase + p*8) = val;
        }
    }
}

// ---------------- MFMA flash attention, transposed flow ----------------------
__global__ __launch_bounds__(256) void attn_mfma(
    const unsigned short* __restrict__ Qg,
    const unsigned short* __restrict__ Kg,
    const unsigned short* __restrict__ Vg,
    unsigned short* __restrict__ o)           // bf16 [s*B+b][256]
{
    const int id = blockIdx.x;                // 0..1023
    const int sl = id >> 3;
    const int bh = (id & 7) * 4 + (sl >> 5);  // XCD (id&7) gets bh in [4x, 4x+4)
    const int qt = sl & 31;
    const int h  = bh & 7;
    const int b  = bh >> 3;
    const int q0 = qt * 64;
    const int tid  = threadIdx.x;
    const int w    = tid >> 6;
    const int lane = tid & 63;
    const int col  = lane & 15;
    const int quad = lane >> 4;

    __shared__ unsigned short Kt[2][64][40];  // [key][d]
    __shared__ unsigned short Vt[2][32][72];  // [d][key]
    __shared__ unsigned short Pt[4][16][72];  // per-wave P [q][key]

    const int q = q0 + 16*w + col;
    bf16x8 qf = *(const bf16x8*)(Qg + ((size_t)(bh*SEQ + q))*DH + quad*8);

    f32x4 O0 = {0.f,0.f,0.f,0.f};
    f32x4 O1 = {0.f,0.f,0.f,0.f};
    float lsum = 0.f;

    const int kRow = tid >> 2, kCh = (tid & 3) * 8;
    const int vD   = tid >> 3, vCh = (tid & 7) * 8;

    const int nT = 16 + ((q0 >= MPOS) ? 1 : 0);
    uint4 kreg = *(const uint4*)(Kg + ((size_t)(bh*SEQ + kRow))*DH + kCh);
    uint4 vreg = *(const uint4*)(Vg + ((size_t)(bh*DH + vD))*SEQ + vCh);

    for (int kt = 0; kt < nT; ++kt) {
        const bool self = (kt == 16);
        const int  p    = kt & 1;
        *(uint4*)&Kt[p][kRow][kCh] = kreg;
        *(uint4*)&Vt[p][vD][vCh]   = vreg;
        __syncthreads();
        if (kt + 1 < nT) {
            int kn = (kt + 1 == 16) ? q0 : (kt + 1)*64;
            kreg = *(const uint4*)(Kg + ((size_t)(bh*SEQ + kn + kRow))*DH + kCh);
            vreg = *(const uint4*)(Vg + ((size_t)(bh*DH + vD))*SEQ + kn + vCh);
        }

        #pragma unroll
        for (int mt = 0; mt < 4; ++mt) {
            bf16x8 kf = *(const bf16x8*)&Kt[p][mt*16 + col][quad*8];
            f32x4 st = {0.f,0.f,0.f,0.f};
            st = __builtin_amdgcn_mfma_f32_16x16x32_bf16(kf, qf, st, 0, 0, 0);
            ushort4 pw;
            #pragma unroll
            for (int i = 0; i < 4; ++i) {
                float pv = __expf(st[i]*ATT_SCALE);
                if (self && (mt*16 + quad*4 + i != 16*w + col)) pv = 0.f;
                unsigned short us = (unsigned short)f2bf(pv);
                ((unsigned short*)&pw)[i] = us;
                lsum += bf2f(us);
            }
            *(ushort4*)&Pt[w][col][mt*16 + quad*4] = pw;
        }
        #pragma unroll
        for (int c = 0; c < 2; ++c) {
            bf16x8 pf = *(const bf16x8*)&Pt[w][col][c*32 + quad*8];
            bf16x8 v0 = *(const bf16x8*)&Vt[p][col     ][c*32 + quad*8];
            bf16x8 v1 = *(const bf16x8*)&Vt[p][col + 16][c*32 + quad*8];
            O0 = __builtin_amdgcn_mfma_f32_16x16x32_bf16(v0, pf, O0, 0, 0, 0);
            O1 = __builtin_amdgcn_mfma_f32_16x16x32_bf16(v1, pf, O1, 0, 0, 0);
        }
    }

    lsum += __shfl_xor(lsum, 16, 64);
    lsum += __shfl_xor(lsum, 32, 64);
    float inv = 1.0f / lsum;
    ushort4 u0, u1;
    #pragma unroll
    for (int i = 0; i < 4; ++i) {
        ((unsigned short*)&u0)[i] = (unsigned short)f2bf(O0[i]*inv);
        ((unsigned short*)&u1)[i] = (unsigned short)f2bf(O1[i]*inv);
    }
    unsigned short* op = o + ((size_t)(q*BATCH + b))*DMODEL + h*DH;
    *(ushort4*)(op + quad*4)      = u0;
    *(ushort4*)(op + 16 + quad*4) = u1;
}

// ------- fused MLP, TWO 16-row groups per block (rows bid*16 and 4096+bid*16) -
// Halves weight-staging amplification (each staged B-frag feeds 8 MFMAs) and
// makes the head stage uniform across all 256 blocks. Grid 256 = 1 block/CU.
__global__ __launch_bounds__(256) void mlp_fused(
    const unsigned short* __restrict__ attb,
    const unsigned short* __restrict__ Wout, const float* __restrict__ ob,
    const float* __restrict__ g1, const float* __restrict__ be1,
    const unsigned short* __restrict__ W1, const float* __restrict__ fb1,
    const unsigned short* __restrict__ W2, const float* __restrict__ fb2,
    const float* __restrict__ g2, const float* __restrict__ be2,
    float* __restrict__ h, unsigned short* __restrict__ hb,
    const unsigned short* __restrict__ Wh1, const float* __restrict__ hb1,
    const float* __restrict__ hw2, const float* __restrict__ hb2,
    float* __restrict__ out, int doHead)
{
    __shared__ unsigned short Bs[3][256][BK];    // 48 KB weight staging
    __shared__ unsigned short As[3][2][16][BK];  // 6 KB activation staging (stage A)
    __shared__ unsigned short Ht[2][16][264];    // LN1-out (later LN2-out) bf16
    __shared__ unsigned short Pt[2][16][520];    // gelu(ff1) bf16
    __shared__ float sP[2][4][16], qP[2][4][16];

    const int tid  = threadIdx.x;
    const int w    = tid >> 6;
    const int lane = tid & 63;
    const int col  = lane & 15;
    const int quad = lane >> 4;
    const int l4   = lane >> 2;
    const int c8   = (lane & 3) * 8;
    const int bid  = blockIdx.x;
    const int m0a  = bid * 16;           // low rows
    const int m0b  = 4096 + bid * 16;    // high rows (head rows)
    const int ma   = m0a + col;
    const int mb   = m0b + col;

    float resid[2][4][4];   // LN1 output per group, residual for stage C

    // ================= stage A: out-proj (K=256) + residual + LN1 =============
    {
        f32x4 acc[2][4];
        #pragma unroll
        for (int g = 0; g < 2; ++g)
            #pragma unroll
            for (int j = 0; j < 4; ++j) acc[g][j] = (f32x4){0.f,0.f,0.f,0.f};

        const unsigned short* ga0 = attb + (size_t)(m0a + l4)*DMODEL + c8;
        const unsigned short* ga1 = attb + (size_t)(m0b + l4)*DMODEL + c8;
        const unsigned short* gb  = Wout + (size_t)(w*64 + l4)*DMODEL + c8;
        const int NS = DMODEL / BK;  // 8

        #pragma unroll
        for (int pb = 0; pb < 2; ++pb) {
            int k = pb * BK;
            if (w == 0) {
                gload16(ga0 + k, &As[pb][0][0][0]);
                gload16(ga1 + k, &As[pb][1][0][0]);
            }
            #pragma unroll
            for (int rr = 0; rr < 4; ++rr)
                gload16(gb + k + (size_t)(rr*16)*DMODEL, &Bs[pb][w*64 + rr*16][0]);
        }
        int bcur = 0;
        for (int s = 0; s < NS; ++s) {
            if (s == NS - 1)  { VMWAIT(0); }
            else if (w == 0)  { VMWAIT(6); }
            else              { VMWAIT(4); }
            pipe_barrier();
            if (s + 2 < NS) {
                int bpre = bcur + 2; if (bpre >= 3) bpre -= 3;
                int k2 = (s + 2) * BK;
                if (w == 0) {
                    gload16(ga0 + k2, &As[bpre][0][0][0]);
                    gload16(ga1 + k2, &As[bpre][1][0][0]);
                }
                #pragma unroll
                for (int rr = 0; rr < 4; ++rr)
                    gload16(gb + k2 + (size_t)(rr*16)*DMODEL, &Bs[bpre][w*64 + rr*16][0]);
            }
            bf16x8 af0 = *(const bf16x8*)&As[bcur][0][col][quad*8];
            bf16x8 af1 = *(const bf16x8*)&As[bcur][1][col][quad*8];
            #pragma unroll
            for (int j = 0; j < 4; ++j) {
                bf16x8 bfr = *(const bf16x8*)&Bs[bcur][w*64 + j*16 + col][quad*8];
                acc[0][j] = __builtin_amdgcn_mfma_f32_16x16x32_bf16(bfr, af0, acc[0][j], 0, 0, 0);
                acc[1][j] = __builtin_amdgcn_mfma_f32_16x16x32_bf16(bfr, af1, acc[1][j], 0, 0, 0);
            }
            bcur = (bcur == 2) ? 0 : bcur + 1;
        }

        float ssum[2] = {0.f, 0.f}, qsum[2] = {0.f, 0.f};
        #pragma unroll
        for (int g = 0; g < 2; ++g) {
            int m = g ? mb : ma;
            #pragma unroll
            for (int j = 0; j < 4; ++j) {
                int n = w*64 + j*16 + quad*4;
                float4 bi = *(const float4*)&ob[n];
                float4 hv = *(const float4*)&h[(size_t)m*DMODEL + n];
                #pragma unroll
                for (int i = 0; i < 4; ++i) {
                    float val = acc[g][j][i] + ((const float*)&bi)[i] + ((const float*)&hv)[i];
                    resid[g][j][i] = val;
                    ssum[g] += val; qsum[g] += val*val;
                }
            }
        }
        #pragma unroll
        for (int g = 0; g < 2; ++g) {
            ssum[g] += __shfl_xor(ssum[g], 16, 64); ssum[g] += __shfl_xor(ssum[g], 32, 64);
            qsum[g] += __shfl_xor(qsum[g], 16, 64); qsum[g] += __shfl_xor(qsum[g], 32, 64);
        }
        if (quad == 0) {
            sP[0][w][col] = ssum[0]; qP[0][w][col] = qsum[0];
            sP[1][w][col] = ssum[1]; qP[1][w][col] = qsum[1];
        }
        __syncthreads();
        #pragma unroll
        for (int g = 0; g < 2; ++g) {
            float st = sP[g][0][col] + sP[g][1][col] + sP[g][2][col] + sP[g][3][col];
            float qt = qP[g][0][col] + qP[g][1][col] + qP[g][2][col] + qP[g][3][col];
            float mu   = st * (1.0f/DMODEL);
            float var  = qt * (1.0f/DMODEL) - mu*mu;
            float rstd = rsqrtf(var + 1e-5f);
            #pragma unroll
            for (int j = 0; j < 4; ++j) {
                int n = w*64 + j*16 + quad*4;
                float4 gv = *(const float4*)&g1[n];
                float4 bv = *(const float4*)&be1[n];
                ushort4 u;
                #pragma unroll
                for (int i = 0; i < 4; ++i) {
                    float o = (resid[g][j][i]-mu)*rstd*((const float*)&gv)[i] + ((const float*)&bv)[i];
                    resid[g][j][i] = o;
                    ((unsigned short*)&u)[i] = (unsigned short)f2bf(o);
                }
                *(ushort4*)&Ht[g][col][n] = u;
            }
        }
        __syncthreads();   // Ht visible to all waves
    }

    // ================= stage B: ff1 (K=256, N=512 in two halves) + gelu =======
    #pragma unroll 1
    for (int nh = 0; nh < 2; ++nh) {
        f32x4 acc[2][4];
        #pragma unroll
        for (int g = 0; g < 2; ++g)
            #pragma unroll
            for (int j = 0; j < 4; ++j) acc[g][j] = (f32x4){0.f,0.f,0.f,0.f};
        const unsigned short* gb = W1 + (size_t)(nh*256 + w*64 + l4)*DMODEL + c8;
        const int NS = DMODEL / BK;  // 8

        #pragma unroll
        for (int pb = 0; pb < 2; ++pb)
            #pragma unroll
            for (int rr = 0; rr < 4; ++rr)
                gload16(gb + pb*BK + (size_t)(rr*16)*DMODEL, &Bs[pb][w*64 + rr*16][0]);

        int bcur = 0;
        for (int s = 0; s < NS; ++s) {
            if (s == NS - 1) { VMWAIT(0); } else { VMWAIT(4); }
            pipe_barrier();
            if (s + 2 < NS) {
                int bpre = bcur + 2; if (bpre >= 3) bpre -= 3;
                int k2 = (s + 2) * BK;
                #pragma unroll
                for (int rr = 0; rr < 4; ++rr)
                    gload16(gb + k2 + (size_t)(rr*16)*DMODEL, &Bs[bpre][w*64 + rr*16][0]);
            }
            bf16x8 af0 = *(const bf16x8*)&Ht[0][col][s*BK + quad*8];
            bf16x8 af1 = *(const bf16x8*)&Ht[1][col][s*BK + quad*8];
            #pragma unroll
            for (int j = 0; j < 4; ++j) {
                bf16x8 bfr = *(const bf16x8*)&Bs[bcur][w*64 + j*16 + col][quad*8];
                acc[0][j] = __builtin_amdgcn_mfma_f32_16x16x32_bf16(bfr, af0, acc[0][j], 0, 0, 0);
                acc[1][j] = __builtin_amdgcn_mfma_f32_16x16x32_bf16(bfr, af1, acc[1][j], 0, 0, 0);
            }
            bcur = (bcur == 2) ? 0 : bcur + 1;
        }
        #pragma unroll
        for (int g = 0; g < 2; ++g)
            #pragma unroll
            for (int j = 0; j < 4; ++j) {
                int n2 = nh*256 + w*64 + j*16 + quad*4;
                float4 bi = *(const float4*)&fb1[n2];
                ushort4 u;
                #pragma unroll
                for (int i = 0; i < 4; ++i)
                    ((unsigned short*)&u)[i] = (unsigned short)f2bf(gelu_exact(acc[g][j][i] + ((const float*)&bi)[i]));
                *(ushort4*)&Pt[g][col][n2] = u;
            }
        pipe_barrier();   // all waves past Bs reads before next half's staging
    }

    // ================= stage C: ff2 (K=512) + residual + LN2 ==================
    {
        __syncthreads();  // Pt visible
        f32x4 acc[2][4];
        #pragma unroll
        for (int g = 0; g < 2; ++g)
            #pragma unroll
            for (int j = 0; j < 4; ++j) acc[g][j] = (f32x4){0.f,0.f,0.f,0.f};
        const unsigned short* gb = W2 + (size_t)(w*64 + l4)*DFF + c8;
        const int NS = DFF / BK;  // 16

        #pragma unroll
        for (int pb = 0; pb < 2; ++pb)
            #pragma unroll
            for (int rr = 0; rr < 4; ++rr)
                gload16(gb + pb*BK + (size_t)(rr*16)*DFF, &Bs[pb][w*64 + rr*16][0]);

        int bcur = 0;
        for (int s = 0; s < NS; ++s) {
            if (s == NS - 1) { VMWAIT(0); } else { VMWAIT(4); }
            pipe_barrier();
            if (s + 2 < NS) {
                int bpre = bcur + 2; if (bpre >= 3) bpre -= 3;
                int k2 = (s + 2) * BK;
                #pragma unroll
                for (int rr = 0; rr < 4; ++rr)
                    gload16(gb + k2 + (size_t)(rr*16)*DFF, &Bs[bpre][w*64 + rr*16][0]);
            }
            bf16x8 af0 = *(const bf16x8*)&Pt[0][col][s*BK + quad*8];
            bf16x8 af1 = *(const bf16x8*)&Pt[1][col][s*BK + quad*8];
            #pragma unroll
            for (int j = 0; j < 4; ++j) {
                bf16x8 bfr = *(const bf16x8*)&Bs[bcur][w*64 + j*16 + col][quad*8];
                acc[0][j] = __builtin_amdgcn_mfma_f32_16x16x32_bf16(bfr, af0, acc[0][j], 0, 0, 0);
                acc[1][j] = __builtin_amdgcn_mfma_f32_16x16x32_bf16(bfr, af1, acc[1][j], 0, 0, 0);
            }
            bcur = (bcur == 2) ? 0 : bcur + 1;
        }

        float ssum[2] = {0.f, 0.f}, qsum[2] = {0.f, 0.f};
        #pragma unroll
        for (int g = 0; g < 2; ++g)
            #pragma unroll
            for (int j = 0; j < 4; ++j) {
                int n = w*64 + j*16 + quad*4;
                float4 bi = *(const float4*)&fb2[n];
                #pragma unroll
                for (int i = 0; i < 4; ++i) {
                    float val = acc[g][j][i] + ((const float*)&bi)[i] + resid[g][j][i];
                    resid[g][j][i] = val;
                    ssum[g] += val; qsum[g] += val*val;
                }
            }
        #pragma unroll
        for (int g = 0; g < 2; ++g) {
            ssum[g] += __shfl_xor(ssum[g], 16, 64); ssum[g] += __shfl_xor(ssum[g], 32, 64);
            qsum[g] += __shfl_xor(qsum[g], 16, 64); qsum[g] += __shfl_xor(qsum[g], 32, 64);
        }
        if (quad == 0) {
            sP[0][w][col] = ssum[0]; qP[0][w][col] = qsum[0];
            sP[1][w][col] = ssum[1]; qP[1][w][col] = qsum[1];
        }
        __syncthreads();
        #pragma unroll
        for (int g = 0; g < 2; ++g) {
            int m = g ? mb : ma;
            float st = sP[g][0][col] + sP[g][1][col] + sP[g][2][col] + sP[g][3][col];
            float qt = qP[g][0][col] + qP[g][1][col] + qP[g][2][col] + qP[g][3][col];
            float mu   = st * (1.0f/DMODEL);
            float var  = qt * (1.0f/DMODEL) - mu*mu;
            float rstd = rsqrtf(var + 1e-5f);
            #pragma unroll
            for (int j = 0; j < 4; ++j) {
                int n = w*64 + j*16 + quad*4;
                float4 gv = *(const float4*)&g2[n];
                float4 bv = *(const float4*)&be2[n];
                float4 o;
                ushort4 u;
                #pragma unroll
                for (int i = 0; i < 4; ++i) {
                    float ov = (resid[g][j][i]-mu)*rstd*((const float*)&gv)[i] + ((const float*)&bv)[i];
                    ((float*)&o)[i] = ov;
                    ((unsigned short*)&u)[i] = (unsigned short)f2bf(ov);
                }
                *(float4*)&h[(size_t)m*DMODEL + n] = o;
                *(ushort4*)(hb + (size_t)m*DMODEL + n) = u;
                *(ushort4*)&Ht[g][col][n] = u;   // LN2 bf16 for head
            }
        }
        __syncthreads();
    }

    // ================= stage D: head (layer 1; every block owns 16 head rows) =
    if (doHead) {
        float sdot = 0.f;
        #pragma unroll 1
        for (int nh = 0; nh < 2; ++nh) {
            f32x4 acc[4];
            #pragma unroll
            for (int j = 0; j < 4; ++j) acc[j] = (f32x4){0.f,0.f,0.f,0.f};
            const unsigned short* gb = Wh1 + (size_t)(nh*256 + w*64 + l4)*DMODEL + c8;
            const int NS = DMODEL / BK;  // 8

            #pragma unroll
            for (int pb = 0; pb < 2; ++pb)
                #pragma unroll
                for (int rr = 0; rr < 4; ++rr)
                    gload16(gb + pb*BK + (size_t)(rr*16)*DMODEL, &Bs[pb][w*64 + rr*16][0]);

            int bcur = 0;
            for (int s = 0; s < NS; ++s) {
                if (s == NS - 1) { VMWAIT(0); } else { VMWAIT(4); }
                pipe_barrier();
                if (s + 2 < NS) {
                    int bpre = bcur + 2; if (bpre >= 3) bpre -= 3;
                    int k2 = (s + 2) * BK;
                    #pragma unroll
                    for (int rr = 0; rr < 4; ++rr)
                        gload16(gb + k2 + (size_t)(rr*16)*DMODEL, &Bs[bpre][w*64 + rr*16][0]);
                }
                bf16x8 af = *(const bf16x8*)&Ht[1][col][s*BK + quad*8];
                #pragma unroll
                for (int j = 0; j < 4; ++j) {
                    bf16x8 bfr = *(const bf16x8*)&Bs[bcur][w*64 + j*16 + col][quad*8];
                    acc[j] = __builtin_amdgcn_mfma_f32_16x16x32_bf16(bfr, af, acc[j], 0, 0, 0);
                }
                bcur = (bcur == 2) ? 0 : bcur + 1;
            }
            #pragma unroll
            for (int j = 0; j < 4; ++j) {
                int n2 = nh*256 + w*64 + j*16 + quad*4;
                float4 b1v = *(const float4*)&hb1[n2];
                float4 w2v = *(const float4*)&hw2[n2];
                #pragma unroll
                for (int i = 0; i < 4; ++i)
                    sdot += gelu_exact(acc[j][i] + ((const float*)&b1v)[i]) * ((const float*)&w2v)[i];
            }
            pipe_barrier();
        }
        sdot += __shfl_xor(sdot, 16, 64); sdot += __shfl_xor(sdot, 32, 64);
        if (quad == 0) sP[0][w][col] = sdot;
        __syncthreads();
        if (tid < 16)
            out[bid*16 + tid] = sP[0][0][tid] + sP[0][1][tid] + sP[0][2][tid] + sP[0][3][tid] + hb2[0];
    }
}

extern "C" void kernel_launch(void* const* d_in, const int* in_sizes, int n_in,
                              void* d_out, int out_size, void* d_ws, size_t ws_size,
                              hipStream_t stream)
{
    const float* x        = (const float*)d_in[0];
    const float* y        = (const float*)d_in[1];
    const float* xenc_w   = (const float*)d_in[3];
    const float* xenc_b   = (const float*)d_in[4];
    const float* yenc_w   = (const float*)d_in[5];
    const float* yenc_b   = (const float*)d_in[6];
    const float* in_proj_w  = (const float*)d_in[7];
    const float* in_proj_b  = (const float*)d_in[8];
    const float* out_proj_w = (const float*)d_in[9];
    const float* out_proj_b = (const float*)d_in[10];
    const float* ln1_g    = (const float*)d_in[11];
    const float* ln1_b    = (const float*)d_in[12];
    const float* lin1_w   = (const float*)d_in[13];
    const float* lin1_b   = (const float*)d_in[14];
    const float* lin2_w   = (const float*)d_in[15];
    const float* lin2_b   = (const float*)d_in[16];
    const float* ln2_g    = (const float*)d_in[17];
    const float* ln2_b    = (const float*)d_in[18];
    const float* head_w1  = (const float*)d_in[19];
    const float* head_b1  = (const float*)d_in[20];
    const float* head_w2  = (const float*)d_in[21];
    const float* head_b2  = (const float*)d_in[22];
    float* out = (float*)d_out;

    // ---- workspace layout ----
    float* ws  = (float*)d_ws;
    float* h    = ws;                                           // 8 MB f32
    unsigned short* hb    = (unsigned short*)(h + (size_t)ROWS*DMODEL);
    unsigned short* attb  = hb    + (size_t)ROWS*DMODEL;
    unsigned short* Qg    = attb  + (size_t)ROWS*DMODEL;
    unsigned short* Kg    = Qg    + (size_t)BATCH*NHEAD*SEQ*DH;
    unsigned short* Vg    = Kg    + (size_t)BATCH*NHEAD*SEQ*DH;
    unsigned short* Wqkv  = Vg    + (size_t)BATCH*NHEAD*SEQ*DH;
    unsigned short* Wout  = Wqkv  + (size_t)NLAYER*3*DMODEL*DMODEL;
    unsigned short* Wl1   = Wout  + (size_t)NLAYER*DMODEL*DMODEL;
    unsigned short* Wl2   = Wl1   + (size_t)NLAYER*DFF*DMODEL;
    unsigned short* Wh1   = Wl2   + (size_t)NLAYER*DMODEL*DFF;

    encode_cast<<<ROWS + 576, 256, 0, stream>>>(
        x, y, xenc_w, xenc_b, yenc_w, yenc_b, h, hb,
        in_proj_w, out_proj_w, lin1_w, lin2_w, head_w1,
        Wqkv, Wout, Wl1, Wl2, Wh1);

    for (int l = 0; l < NLAYER; ++l) {
        gemm_qkv<<<dim3(12, ROWS/128), 256, 0, stream>>>(
            hb, Wqkv + (size_t)l*3*DMODEL*DMODEL, in_proj_b + l*3*DMODEL,
            Qg, Kg, Vg, DMODEL);
        attn_mfma<<<dim3(SEQ/64 * NHEAD * BATCH), 256, 0, stream>>>(Qg, Kg, Vg, attb);
        mlp_fused<<<256, 256, 0, stream>>>(
            attb,
            Wout + (size_t)l*DMODEL*DMODEL, out_proj_b + l*DMODEL,
            ln1_g + l*DMODEL, ln1_b + l*DMODEL,
            Wl1 + (size_t)l*DFF*DMODEL, lin1_b + l*DFF,
            Wl2 + (size_t)l*DMODEL*DFF, lin2_b + l*DMODEL,
            ln2_g + l*DMODEL, ln2_b + l*DMODEL,
            h, hb,
            Wh1, head_b1, head_w2, head_b2,
            out, (l == NLAYER-1) ? 1 : 0);
    }
}